// Round 3
// baseline (226.197 us; speedup 1.0000x reference)
//
#include <hip/hip_runtime.h>
#include <hip/hip_bf16.h>

#define HH 12
#define DD 64
#define NB1 28
#define NB2 52
#define NF 2
#define FB1 56           // NF*NB1
#define FB2 104          // NF*NB2
#define STRIDE_HD 768    // HH*DD
#define SCALEF 0.125f

typedef float f32x4 __attribute__((ext_vector_type(4)));
typedef float f32x16 __attribute__((ext_vector_type(16)));
typedef short bf16x8 __attribute__((ext_vector_type(8)));

#if __has_builtin(__builtin_amdgcn_exp2f)
#define EXP2(x) __builtin_amdgcn_exp2f(x)
#else
#define EXP2(x) __expf((x) * 0.6931471805599453f)
#endif

__device__ __forceinline__ unsigned short f2bf(float x) {
  union { float f; unsigned u; } c; c.f = x;
  unsigned r = c.u + 0x7fffu + ((c.u >> 16) & 1u);
  return (unsigned short)(r >> 16);
}

// ---------------------------------------------------------------------------
// Fused blin(+rope) + tiny SDPA + output rope for one (group, head).
// ---------------------------------------------------------------------------
template<int NK, int GD, int GMUL, int KSTR>
__global__ __launch_bounds__(256)
void k_small(const float* __restrict__ X,
             const float* __restrict__ cosb, const float* __restrict__ sinb,
             const float* __restrict__ Wq, const float* __restrict__ bq,
             const float* __restrict__ Wk, const float* __restrict__ bk,
             const float* __restrict__ Wv, const float* __restrict__ bv,
             float* __restrict__ outb) {
  const int n = blockIdx.x, h = blockIdx.y;
  const int tid = threadIdx.x;
  const int f = n / GD, g = n % GD;
  const int s_base = f * (NB1 * NB2) + g * GMUL;

  __shared__ __align__(16) float xs[NK][DD + 4];
  __shared__ float Ks[NK][DD + 1];
  __shared__ float Vs[NK][DD + 1];
  __shared__ float qs[DD];
  __shared__ float ps[64];

  for (int idx = tid; idx < NK * DD; idx += 256) {
    int r = idx >> 6, d = idx & 63;
    xs[r][d] = X[(size_t)(s_base + r * KSTR) * STRIDE_HD + h * DD + d];
  }
  __syncthreads();

  const int m  = tid >> 3;   // e-pair 0..31
  const int rg = tid & 7;    // row group 0..7
  const float* WkH = Wk + (size_t)h * DD * DD;
  const float* WvH = Wv + (size_t)h * DD * DD;
  const float bk0 = bk[h * DD + 2 * m], bk1 = bk[h * DD + 2 * m + 1];
  const float bv0 = bv[h * DD + 2 * m], bv1 = bv[h * DD + 2 * m + 1];
  const float4* wk0 = (const float4*)(WkH + (2 * m) * DD);
  const float4* wk1 = (const float4*)(WkH + (2 * m + 1) * DD);
  const float4* wv0 = (const float4*)(WvH + (2 * m) * DD);
  const float4* wv1 = (const float4*)(WvH + (2 * m + 1) * DD);

  for (int base = 0; base < NK; base += 16) {
    for (int rr = 0; rr < 2; ++rr) {
      int r = base + 2 * rg + rr;
      if (r < NK) {
        float k0 = bk0, k1 = bk1, v0 = bv0, v1 = bv1;
        const float4* x4 = (const float4*)xs[r];
        #pragma unroll
        for (int d4 = 0; d4 < 16; ++d4) {
          float4 xv = x4[d4];
          float4 a = wk0[d4], b = wk1[d4], c = wv0[d4], e = wv1[d4];
          k0 += xv.x * a.x + xv.y * a.y + xv.z * a.z + xv.w * a.w;
          k1 += xv.x * b.x + xv.y * b.y + xv.z * b.z + xv.w * b.w;
          v0 += xv.x * c.x + xv.y * c.y + xv.z * c.z + xv.w * c.w;
          v1 += xv.x * e.x + xv.y * e.y + xv.z * e.z + xv.w * e.w;
        }
        int srow = s_base + r * KSTR;
        float co = cosb[srow * 32 + m], si = sinb[srow * 32 + m];
        Ks[r][2 * m]     = k0 * co - k1 * si;
        Ks[r][2 * m + 1] = k1 * co + k0 * si;
        Vs[r][2 * m]     = v0;
        Vs[r][2 * m + 1] = v1;
      }
    }
  }
  if (rg == 0) {
    float q0 = bq[h * DD + 2 * m], q1 = bq[h * DD + 2 * m + 1];
    const float4* x4 = (const float4*)xs[0];
    const float4* w0 = (const float4*)(Wq + (size_t)h * DD * DD + (2 * m) * DD);
    const float4* w1 = (const float4*)(Wq + (size_t)h * DD * DD + (2 * m + 1) * DD);
    #pragma unroll
    for (int d4 = 0; d4 < 16; ++d4) {
      float4 xv = x4[d4];
      float4 a = w0[d4], b = w1[d4];
      q0 += xv.x * a.x + xv.y * a.y + xv.z * a.z + xv.w * a.w;
      q1 += xv.x * b.x + xv.y * b.y + xv.z * b.z + xv.w * b.w;
    }
    float co = cosb[s_base * 32 + m], si = sinb[s_base * 32 + m];
    qs[2 * m]     = q0 * co - q1 * si;
    qs[2 * m + 1] = q1 * co + q0 * si;
  }
  __syncthreads();

  if (tid < 64) {
    float sc = -1e30f;
    if (tid < NK) {
      float acc2 = 0.f;
      const float* kr = Ks[tid];
      #pragma unroll 8
      for (int d = 0; d < DD; ++d) acc2 += qs[d] * kr[d];
      sc = acc2 * SCALEF;
    }
    float mx = sc;
    for (int o = 32; o; o >>= 1) mx = fmaxf(mx, __shfl_xor(mx, o));
    float e = (tid < NK) ? __expf(sc - mx) : 0.f;
    float sm = e;
    for (int o = 32; o; o >>= 1) sm += __shfl_xor(sm, o);
    if (tid < NK) ps[tid] = e / sm;
  }
  __syncthreads();

  if (tid < 32) {
    float o0 = 0.f, o1 = 0.f;
    for (int r = 0; r < NK; ++r) {
      float p = ps[r];
      o0 += p * Vs[r][2 * tid];
      o1 += p * Vs[r][2 * tid + 1];
    }
    float co = cosb[s_base * 32 + tid], si = sinb[s_base * 32 + tid];
    outb[(size_t)n * STRIDE_HD + h * DD + 2 * tid]     = o0 * co - o1 * si;
    outb[(size_t)n * STRIDE_HD + h * DD + 2 * tid + 1] = o1 * co + o0 * si;
  }
}

// ---------------------------------------------------------------------------
// L: 2x2 register-blocked
// ---------------------------------------------------------------------------
__global__ __launch_bounds__(256)
void k_L(const float* __restrict__ lq, const float* __restrict__ cosb,
         const float* __restrict__ sinb, const float* __restrict__ lk_out,
         float* __restrict__ Lbuf) {
  const int bid = blockIdx.x;              // h*104 + a*52 + j
  const int h = bid / (NF * NB2);
  const int rem = bid % (NF * NB2);
  const int a = rem / NB2, j = rem % NB2;
  const int tid = threadIdx.x;
  __shared__ __align__(16) float qs[NB1][DD + 4];
  __shared__ __align__(16) float ks[FB1][DD + 4];
  for (int idx = tid; idx < NB1 * 32; idx += 256) {
    int i = idx >> 5, mm = idx & 31;
    int srow = a * (NB1 * NB2) + i * NB2 + j;
    const float* xr = lq + (size_t)srow * STRIDE_HD + h * DD;
    float x0 = xr[2 * mm], x1 = xr[2 * mm + 1];
    float co = cosb[srow * 32 + mm], si = sinb[srow * 32 + mm];
    qs[i][2 * mm]     = x0 * co - x1 * si;
    qs[i][2 * mm + 1] = x1 * co + x0 * si;
  }
  for (int idx = tid; idx < FB1 * DD; idx += 256) {
    int r = idx >> 6, d = idx & 63;
    ks[r][d] = lk_out[(size_t)r * STRIDE_HD + h * DD + d];
  }
  __syncthreads();
  for (int t = tid; t < NF * 14 * 14; t += 256) {   // 392 2x2 tiles
    int ff = t / 196, rr = t % 196;
    int it = rr / 14, kt = rr % 14;
    const float4* q0 = (const float4*)qs[2 * it];
    const float4* q1 = (const float4*)qs[2 * it + 1];
    const float4* k0 = (const float4*)ks[ff * NB1 + 2 * kt];
    const float4* k1 = (const float4*)ks[ff * NB1 + 2 * kt + 1];
    float a00 = 0.f, a01 = 0.f, a10 = 0.f, a11 = 0.f;
    #pragma unroll
    for (int d4 = 0; d4 < 16; ++d4) {
      float4 qa = q0[d4], qb = q1[d4], ka = k0[d4], kb = k1[d4];
      a00 += qa.x * ka.x + qa.y * ka.y + qa.z * ka.z + qa.w * ka.w;
      a01 += qa.x * kb.x + qa.y * kb.y + qa.z * kb.z + qa.w * kb.w;
      a10 += qb.x * ka.x + qb.y * ka.y + qb.z * ka.z + qb.w * ka.w;
      a11 += qb.x * kb.x + qb.y * kb.y + qb.z * kb.z + qb.w * kb.w;
    }
    size_t ob = (size_t)bid * (NF * NB1 * NB1) + (size_t)ff * (NB1 * NB1);
    Lbuf[ob + (size_t)(2 * it) * NB1 + 2 * kt]         = a00;
    Lbuf[ob + (size_t)(2 * it) * NB1 + 2 * kt + 1]     = a01;
    Lbuf[ob + (size_t)(2 * it + 1) * NB1 + 2 * kt]     = a10;
    Lbuf[ob + (size_t)(2 * it + 1) * NB1 + 2 * kt + 1] = a11;
  }
}

// ---------------------------------------------------------------------------
// R: 2x2 register-blocked
// ---------------------------------------------------------------------------
__global__ __launch_bounds__(256)
void k_R(const float* __restrict__ rk, const float* __restrict__ cosb,
         const float* __restrict__ sinb, const float* __restrict__ rq_out,
         float* __restrict__ Rbuf) {
  const int bid = blockIdx.x;              // h*56 + fk
  const int h = bid / FB1;
  const int fk = bid % FB1;
  const int f = fk / NB1, k = fk % NB1;
  const int tid = threadIdx.x;
  __shared__ __align__(16) float ks[NB2][DD + 4];
  __shared__ __align__(16) float qs[FB2][DD + 4];
  for (int idx = tid; idx < NB2 * 32; idx += 256) {
    int l = idx >> 5, mm = idx & 31;
    int srow = f * (NB1 * NB2) + k * NB2 + l;
    const float* xr = rk + (size_t)srow * STRIDE_HD + h * DD;
    float x0 = xr[2 * mm], x1 = xr[2 * mm + 1];
    float co = cosb[srow * 32 + mm], si = sinb[srow * 32 + mm];
    ks[l][2 * mm]     = x0 * co - x1 * si;
    ks[l][2 * mm + 1] = x1 * co + x0 * si;
  }
  for (int idx = tid; idx < FB2 * DD; idx += 256) {
    int r2 = idx >> 6, d = idx & 63;
    qs[r2][d] = rq_out[(size_t)r2 * STRIDE_HD + h * DD + d];
  }
  __syncthreads();
  for (int t = tid; t < NF * 26 * 26; t += 256) {   // 1352 2x2 tiles
    int aa = t / 676, rr = t % 676;
    int jt = rr / 26, lt = rr % 26;
    const float4* q0 = (const float4*)qs[aa * NB2 + 2 * jt];
    const float4* q1 = (const float4*)qs[aa * NB2 + 2 * jt + 1];
    const float4* k0 = (const float4*)ks[2 * lt];
    const float4* k1 = (const float4*)ks[2 * lt + 1];
    float a00 = 0.f, a01 = 0.f, a10 = 0.f, a11 = 0.f;
    #pragma unroll
    for (int d4 = 0; d4 < 16; ++d4) {
      float4 qa = q0[d4], qb = q1[d4], ka = k0[d4], kb = k1[d4];
      a00 += qa.x * ka.x + qa.y * ka.y + qa.z * ka.z + qa.w * ka.w;
      a01 += qa.x * kb.x + qa.y * kb.y + qa.z * kb.z + qa.w * kb.w;
      a10 += qb.x * ka.x + qb.y * ka.y + qb.z * ka.z + qb.w * ka.w;
      a11 += qb.x * kb.x + qb.y * kb.y + qb.z * kb.z + qb.w * kb.w;
    }
    size_t row0 = ((size_t)(h * NF + aa) * NB2 + 2 * jt) * (size_t)(NF * NB1 * NB2);
    size_t row1 = row0 + (size_t)(NF * NB1 * NB2);
    size_t cb = (size_t)fk * NB2 + 2 * lt;
    Rbuf[row0 + cb]     = a00;
    Rbuf[row0 + cb + 1] = a01;
    Rbuf[row1 + cb]     = a10;
    Rbuf[row1 + cb + 1] = a11;
  }
}

// ---------------------------------------------------------------------------
// v (S,H,D) f32 -> vb[(h*64+d)*56 + fk][l 0..63] bf16, l>=52 zero padded
// ---------------------------------------------------------------------------
__global__ __launch_bounds__(256)
void k_vb(const float* __restrict__ v, unsigned short* __restrict__ vb) {
  const int fk = blockIdx.x;
  const int h = blockIdx.y;
  const int tid = threadIdx.x;
  __shared__ float tile[NB2][DD + 8];
  for (int idx = tid; idx < NB2 * DD; idx += 256) {
    int l = idx >> 6, d = idx & 63;
    tile[l][d] = v[(size_t)(fk * NB2 + l) * STRIDE_HD + h * DD + d];
  }
  __syncthreads();
  for (int idx = tid; idx < DD * 64; idx += 256) {
    int d = idx >> 6, l = idx & 63;
    float val = (l < NB2) ? tile[l][d] : 0.f;
    vb[((size_t)(h * DD + d) * FB1 + fk) * 64 + l] = f2bf(val);
  }
}

// ---------------------------------------------------------------------------
// Register-P flash attention: P computed in MFMA A-fragment layout, no LDS
// round-trip, no in-loop barriers. 32x32x16 MFMA; waves = 2 d-halves x 2 fk
// segments; epilogue combines segments through an 8KB LDS exchange.
// ---------------------------------------------------------------------------
__global__ __launch_bounds__(256)
void k_main(const float* __restrict__ Lbuf, const float* __restrict__ Rbuf,
            const unsigned short* __restrict__ vb, float* __restrict__ outp) {
  const int bid = blockIdx.x;          // h*104 + a*52 + j
  const int h = bid / (NF * NB2);
  const int rem = bid % (NF * NB2);
  const int a = rem / NB2, j = rem % NB2;
  const int tid = threadIdx.x;
  const int lane = tid & 63;
  const int w = tid >> 6;
  const int half = w & 1;              // d-half: d = half*32 + (lane&31)
  const int seg = w >> 1;              // fk segment: fk = seg*28 + t

  __shared__ __align__(16) float Ls2T[NF][NB1][32];  // [ff][kk][i], *SCALEF*log2e, i>=28 -> 0
  __shared__ __align__(16) float Rs[FB1][64];        // l>=52 garbage (masked in loop)
  __shared__ float m2s[32];
  __shared__ float Rmx[FB1], Rmn[FB1];

  const float SC = SCALEF * 1.44269504f;
  for (int idx = tid; idx < NF * NB1 * NB1; idx += 256) {
    int ff = idx / (NB1 * NB1), r2 = idx % (NB1 * NB1);
    int i = r2 / NB1, kk = r2 % NB1;
    Ls2T[ff][kk][i] = Lbuf[(size_t)bid * (NF * NB1 * NB1) + idx] * SC;
  }
  for (int idx = tid; idx < NF * NB1 * 4; idx += 256) {   // zero pad rows 28..31
    int ff = idx / (NB1 * 4), r2 = idx % (NB1 * 4);
    Ls2T[ff][r2 >> 2][28 + (r2 & 3)] = 0.f;
  }
  for (int idx = tid; idx < FB1 * 13; idx += 256) {       // 728 float4 copies
    int fk = idx / 13, lc = idx % 13;
    float4 vv = ((const float4*)(Rbuf + (size_t)bid * (NF * NB1 * NB2)))[idx];
    *(float4*)&Rs[fk][lc * 4] = vv;
  }
  if (tid >= 224) m2s[tid - 224] = 0.f;                   // pad rows' m2
  __syncthreads();

  if (tid < 224) {                                        // col max/min of R
    int fk = tid >> 2, part = tid & 3;
    float mx = -1e30f, mn = 1e30f;
    for (int l = part * 13; l < part * 13 + 13; ++l) {
      float x = Rs[fk][l];
      mx = fmaxf(mx, x); mn = fminf(mn, x);
    }
    mx = fmaxf(mx, __shfl_xor(mx, 1)); mn = fminf(mn, __shfl_xor(mn, 1));
    mx = fmaxf(mx, __shfl_xor(mx, 2)); mn = fminf(mn, __shfl_xor(mn, 2));
    if (part == 0) { Rmx[fk] = mx; Rmn[fk] = mn; }
  }
  __syncthreads();

  if (tid < 224) {                                        // exact row max (log2 units)
    int i = tid >> 3, s = tid & 7;
    float m = -1e30f;
    #pragma unroll
    for (int n = 0; n < 7; ++n) {
      int fk = s + 8 * n;
      int ff = (fk >= NB1) ? 1 : 0, kk = fk - ff * NB1;
      float Lv = Ls2T[ff][kk][i];
      m = fmaxf(m, fmaxf(Lv * Rmx[fk], Lv * Rmn[fk]));
    }
    m = fmaxf(m, __shfl_xor(m, 1));
    m = fmaxf(m, __shfl_xor(m, 2));
    m = fmaxf(m, __shfl_xor(m, 4));
    if (s == 0) m2s[i] = m;
  }
  __syncthreads();

  const int row = lane & 31;
  const int hi = lane >> 5;
  const float nm = -m2s[row];
  const int dcol = half * 32 + row;
  const unsigned short* vpp = vb + (size_t)(h * DD + dcol) * (FB1 * 64) + hi * 8;

  f32x16 acc = {0.f,0.f,0.f,0.f, 0.f,0.f,0.f,0.f, 0.f,0.f,0.f,0.f, 0.f,0.f,0.f,0.f};
  float lsum = 0.f;

  for (int t = 0; t < 28; ++t) {
    const int fk = seg * 28 + t;
    const float Lv = Ls2T[seg][t][row];
    const unsigned short* vp = vpp + (size_t)fk * 64;
    #pragma unroll
    for (int ks = 0; ks < 4; ++ks) {
      const int k0 = ks * 16 + hi * 8;
      float4 ra = *(const float4*)&Rs[fk][k0];
      float4 rb = *(const float4*)&Rs[fk][k0 + 4];
      float p0 = EXP2(fmaf(Lv, ra.x, nm));
      float p1 = EXP2(fmaf(Lv, ra.y, nm));
      float p2 = EXP2(fmaf(Lv, ra.z, nm));
      float p3 = EXP2(fmaf(Lv, ra.w, nm));
      float p4 = EXP2(fmaf(Lv, rb.x, nm));
      float p5 = EXP2(fmaf(Lv, rb.y, nm));
      float p6 = EXP2(fmaf(Lv, rb.z, nm));
      float p7 = EXP2(fmaf(Lv, rb.w, nm));
      if (ks == 3) {                       // l = 48 + hi*8 + idx; mask l >= 52
        if (hi == 0) { p4 = 0.f; p5 = 0.f; p6 = 0.f; p7 = 0.f; }
        else { p0 = 0.f; p1 = 0.f; p2 = 0.f; p3 = 0.f;
               p4 = 0.f; p5 = 0.f; p6 = 0.f; p7 = 0.f; }
      }
      lsum += ((p0 + p1) + (p2 + p3)) + ((p4 + p5) + (p6 + p7));
      union { bf16x8 v8; __hip_bfloat162 h2[4]; } pk;
      pk.h2[0] = __float22bfloat162_rn(make_float2(p0, p1));
      pk.h2[1] = __float22bfloat162_rn(make_float2(p2, p3));
      pk.h2[2] = __float22bfloat162_rn(make_float2(p4, p5));
      pk.h2[3] = __float22bfloat162_rn(make_float2(p6, p7));
      bf16x8 bv = *(const bf16x8*)(vp + ks * 16);
      acc = __builtin_amdgcn_mfma_f32_32x32x16_bf16(pk.v8, bv, acc, 0, 0, 0);
    }
  }

  lsum += __shfl_xor(lsum, 32);          // full row sum for this segment
  __syncthreads();                        // all waves done reading Rs/Ls2T

  float* eacc = &Rs[0][0];               // alias: 2*1024 f32 partials + 32 lsum
  float* els  = eacc + 2048;
  if (seg == 1) {
    #pragma unroll
    for (int r = 0; r < 16; ++r) eacc[half * 1024 + r * 64 + lane] = acc[r];
    if (w == 2 && lane < 32) els[lane] = lsum;
  }
  __syncthreads();
  if (seg == 0) {
    float linv = 1.0f / (lsum + els[row]);
    #pragma unroll
    for (int r = 0; r < 16; ++r) {
      float o = acc[r] + eacc[half * 1024 + r * 64 + lane];
      int irow = (r & 3) + 8 * (r >> 2) + 4 * hi;
      float li = __shfl(linv, irow);     // lane irow holds linv for row irow
      if (irow < NB1) {
        int srow = a * (NB1 * NB2) + irow * NB2 + j;
        outp[(size_t)srow * STRIDE_HD + h * DD + dcol] = o * li;
      }
    }
  }
}

// ---------------------------------------------------------------------------
extern "C" void kernel_launch(void* const* d_in, const int* in_sizes, int n_in,
                              void* d_out, int out_size, void* d_ws, size_t ws_size,
                              hipStream_t stream) {
  (void)in_sizes; (void)n_in; (void)out_size; (void)ws_size;
  const float* lq   = (const float*)d_in[0];
  const float* lk   = (const float*)d_in[1];
  const float* rq   = (const float*)d_in[2];
  const float* rk   = (const float*)d_in[3];
  const float* v    = (const float*)d_in[4];
  const float* cosb = (const float*)d_in[5];
  const float* sinb = (const float*)d_in[6];
  const float* W_lkq = (const float*)d_in[7];  const float* b_lkq = (const float*)d_in[8];
  const float* W_lkk = (const float*)d_in[9];  const float* b_lkk = (const float*)d_in[10];
  const float* W_lkv = (const float*)d_in[11]; const float* b_lkv = (const float*)d_in[12];
  const float* W_rqq = (const float*)d_in[13]; const float* b_rqq = (const float*)d_in[14];
  const float* W_rqk = (const float*)d_in[15]; const float* b_rqk = (const float*)d_in[16];
  const float* W_rqv = (const float*)d_in[17]; const float* b_rqv = (const float*)d_in[18];

  float* ws = (float*)d_ws;
  float* lk_out = ws;                                               // 56*768
  float* rq_out = lk_out + (size_t)FB1 * STRIDE_HD;                 // 104*768
  float* Lbuf   = rq_out + (size_t)FB2 * STRIDE_HD;                 // 1248*1568
  float* Rbuf   = Lbuf + (size_t)HH * NF * NB2 * (NF * NB1 * NB1);  // 1248*2912
  unsigned short* vb =
      (unsigned short*)(Rbuf + (size_t)HH * NF * NB2 * (NF * NB1 * NB2)); // 12*64*56*64

  k_small<52, 28, 52, 1><<<dim3(56, 12), 256, 0, stream>>>(
      lk, cosb, sinb, W_lkq, b_lkq, W_lkk, b_lkk, W_lkv, b_lkv, lk_out);
  k_small<28, 52, 1, 52><<<dim3(104, 12), 256, 0, stream>>>(
      rq, cosb, sinb, W_rqq, b_rqq, W_rqk, b_rqk, W_rqv, b_rqv, rq_out);
  k_vb<<<dim3(56, 12), 256, 0, stream>>>(v, vb);
  k_L<<<1248, 256, 0, stream>>>(lq, cosb, sinb, lk_out, Lbuf);
  k_R<<<672, 256, 0, stream>>>(rk, cosb, sinb, rq_out, Rbuf);
  k_main<<<1248, 256, 0, stream>>>(Lbuf, Rbuf, vb, (float*)d_out);
}

// Round 4
// 193.426 us; speedup vs baseline: 1.1694x; 1.1694x over previous
//
#include <hip/hip_runtime.h>
#include <hip/hip_bf16.h>

#define HH 12
#define DD 64
#define NB1 28
#define NB2 52
#define NF 2
#define FB1 56           // NF*NB1
#define FB2 104          // NF*NB2
#define STRIDE_HD 768    // HH*DD
#define SCALEF 0.125f

typedef float f32x4 __attribute__((ext_vector_type(4)));
typedef float f32x16 __attribute__((ext_vector_type(16)));
typedef short bf16x8 __attribute__((ext_vector_type(8)));

#if __has_builtin(__builtin_amdgcn_exp2f)
#define EXP2(x) __builtin_amdgcn_exp2f(x)
#else
#define EXP2(x) __expf((x) * 0.6931471805599453f)
#endif

__device__ __forceinline__ unsigned short f2bf(float x) {
  union { float f; unsigned u; } c; c.f = x;
  unsigned r = c.u + 0x7fffu + ((c.u >> 16) & 1u);
  return (unsigned short)(r >> 16);
}

// ===========================================================================
// FRONT: fused  k_small(lk) + k_small(rq) + V re-layout/cast
// ===========================================================================
struct FrontShared {
  __align__(16) float xs[52][68];   // input rows (also vb tile)
  __align__(16) float Ks[52][65];
  __align__(16) float qs[64];
  float ps[64];
  __align__(16) float ys[64];
};

template<int NK, int GD, int GMUL, int KSTR>
__device__ void small_path(int n, int h, const float* __restrict__ X,
                           const float* __restrict__ cosb, const float* __restrict__ sinb,
                           const float* __restrict__ Wq, const float* __restrict__ bq,
                           const float* __restrict__ Wk, const float* __restrict__ bk,
                           const float* __restrict__ Wv, const float* __restrict__ bv,
                           float* __restrict__ outb, FrontShared& fs) {
  const int tid = threadIdx.x;
  const int f = n / GD, g = n % GD;
  const int s_base = f * (NB1 * NB2) + g * GMUL;

  for (int idx = tid; idx < NK * DD; idx += 256) {
    int r = idx >> 6, d = idx & 63;
    fs.xs[r][d] = X[(size_t)(s_base + r * KSTR) * STRIDE_HD + h * DD + d];
  }
  __syncthreads();

  const int m = tid >> 3, rg = tid & 7;
  {  // K projection + rope
    const float* WkH = Wk + (size_t)h * DD * DD;
    const float bk0 = bk[h * DD + 2 * m], bk1 = bk[h * DD + 2 * m + 1];
    const float4* wk0 = (const float4*)(WkH + (2 * m) * DD);
    const float4* wk1 = (const float4*)(WkH + (2 * m + 1) * DD);
    for (int base = 0; base < NK; base += 16) {
      for (int rr = 0; rr < 2; ++rr) {
        int r = base + 2 * rg + rr;
        if (r < NK) {
          float k0 = bk0, k1 = bk1;
          const float4* x4 = (const float4*)fs.xs[r];
          #pragma unroll
          for (int d4 = 0; d4 < 16; ++d4) {
            float4 xv = x4[d4];
            float4 a = wk0[d4], b = wk1[d4];
            k0 += xv.x * a.x + xv.y * a.y + xv.z * a.z + xv.w * a.w;
            k1 += xv.x * b.x + xv.y * b.y + xv.z * b.z + xv.w * b.w;
          }
          int srow = s_base + r * KSTR;
          float co = cosb[srow * 32 + m], si = sinb[srow * 32 + m];
          fs.Ks[r][2 * m]     = k0 * co - k1 * si;
          fs.Ks[r][2 * m + 1] = k1 * co + k0 * si;
        }
      }
    }
  }
  if (rg == 0) {  // q projection from xs[0]
    float q0 = bq[h * DD + 2 * m], q1 = bq[h * DD + 2 * m + 1];
    const float4* x4 = (const float4*)fs.xs[0];
    const float4* w0 = (const float4*)(Wq + (size_t)h * DD * DD + (2 * m) * DD);
    const float4* w1 = (const float4*)(Wq + (size_t)h * DD * DD + (2 * m + 1) * DD);
    #pragma unroll
    for (int d4 = 0; d4 < 16; ++d4) {
      float4 xv = x4[d4];
      float4 a = w0[d4], b = w1[d4];
      q0 += xv.x * a.x + xv.y * a.y + xv.z * a.z + xv.w * a.w;
      q1 += xv.x * b.x + xv.y * b.y + xv.z * b.z + xv.w * b.w;
    }
    float co = cosb[s_base * 32 + m], si = sinb[s_base * 32 + m];
    fs.qs[2 * m]     = q0 * co - q1 * si;
    fs.qs[2 * m + 1] = q1 * co + q0 * si;
  }
  __syncthreads();

  if (tid < 64) {  // scores + softmax
    float sc = -1e30f;
    if (tid < NK) {
      float acc2 = 0.f;
      const float* kr = fs.Ks[tid];
      #pragma unroll 8
      for (int d = 0; d < DD; ++d) acc2 += fs.qs[d] * kr[d];
      sc = acc2 * SCALEF;
    }
    float mx = sc;
    for (int o = 32; o; o >>= 1) mx = fmaxf(mx, __shfl_xor(mx, o));
    float e = (tid < NK) ? __expf(sc - mx) : 0.f;
    float sm = e;
    for (int o = 32; o; o >>= 1) sm += __shfl_xor(sm, o);
    fs.ps[tid] = (tid < NK) ? e / sm : 0.f;
  }
  __syncthreads();

  if (tid < 64) {  // pooled input row  y = sum_r p_r x_r
    float y = 0.f;
    for (int r = 0; r < NK; ++r) y += fs.ps[r] * fs.xs[r][tid];
    fs.ys[tid] = y;
  }
  __syncthreads();

  if (tid < 32) {  // out = Wv y + bv (since sum p = 1), then rope
    const float* WvH = Wv + (size_t)h * DD * DD;
    float o0 = bv[h * DD + 2 * tid], o1 = bv[h * DD + 2 * tid + 1];
    const float4* w0 = (const float4*)(WvH + (2 * tid) * DD);
    const float4* w1 = (const float4*)(WvH + (2 * tid + 1) * DD);
    const float4* y4 = (const float4*)fs.ys;
    #pragma unroll
    for (int d4 = 0; d4 < 16; ++d4) {
      float4 yv = y4[d4];
      float4 a = w0[d4], b = w1[d4];
      o0 += yv.x * a.x + yv.y * a.y + yv.z * a.z + yv.w * a.w;
      o1 += yv.x * b.x + yv.y * b.y + yv.z * b.z + yv.w * b.w;
    }
    float co = cosb[s_base * 32 + tid], si = sinb[s_base * 32 + tid];
    outb[(size_t)n * STRIDE_HD + h * DD + 2 * tid]     = o0 * co - o1 * si;
    outb[(size_t)n * STRIDE_HD + h * DD + 2 * tid + 1] = o1 * co + o0 * si;
  }
}

// v (S,H,D) f32 -> vb2[h][fk][l8][d][li] bf16 (l = l8*8+li, l>=52 zero)
__device__ void vb_path(int fk, int h, const float* __restrict__ v,
                        unsigned short* __restrict__ vb2, FrontShared& fs) {
  const int tid = threadIdx.x;
  float (*tile)[68] = fs.xs;
  for (int idx = tid; idx < NB2 * DD; idx += 256) {
    int l = idx >> 6, d = idx & 63;
    tile[l][d] = v[(size_t)(fk * NB2 + l) * STRIDE_HD + h * DD + d];
  }
  __syncthreads();
  for (int idx = tid; idx < 512; idx += 256) {
    int l8 = idx >> 6, d = idx & 63;
    unsigned short tmp[8];
    #pragma unroll
    for (int li = 0; li < 8; ++li) {
      int l = l8 * 8 + li;
      tmp[li] = (l < NB2) ? f2bf(tile[l][d]) : (unsigned short)0;
    }
    bf16x8* dst = (bf16x8*)(vb2 + (((size_t)(h * FB1 + fk) * 8 + l8) * 64 + d) * 8);
    *dst = *(bf16x8*)tmp;
  }
}

__global__ __launch_bounds__(256)
void k_front(const float* __restrict__ lk, const float* __restrict__ rq,
             const float* __restrict__ v,
             const float* __restrict__ cosb, const float* __restrict__ sinb,
             const float* __restrict__ W_lkq, const float* __restrict__ b_lkq,
             const float* __restrict__ W_lkk, const float* __restrict__ b_lkk,
             const float* __restrict__ W_lkv, const float* __restrict__ b_lkv,
             const float* __restrict__ W_rqq, const float* __restrict__ b_rqq,
             const float* __restrict__ W_rqk, const float* __restrict__ b_rqk,
             const float* __restrict__ W_rqv, const float* __restrict__ b_rqv,
             float* __restrict__ lk_out, float* __restrict__ rq_out,
             unsigned short* __restrict__ vb2) {
  __shared__ FrontShared fs;
  const int bx = blockIdx.x;
  if (bx < 672) {
    small_path<52, 28, 52, 1>(bx % 56, bx / 56, lk, cosb, sinb,
                              W_lkq, b_lkq, W_lkk, b_lkk, W_lkv, b_lkv, lk_out, fs);
  } else if (bx < 1920) {
    int id = bx - 672;
    small_path<28, 52, 1, 52>(id % 104, id / 104, rq, cosb, sinb,
                              W_rqq, b_rqq, W_rqk, b_rqk, W_rqv, b_rqv, rq_out, fs);
  } else {
    int id = bx - 1920;
    vb_path(id % 56, id / 56, v, vb2, fs);
  }
}

// ===========================================================================
// MID: fused L and R contractions (both 2x2 register-blocked)
// ===========================================================================
struct MidLShared { float qs[NB1][68]; float ks[FB1][68]; };
struct MidRShared { float ks[NB2][68]; float qs[FB2][68]; };
union MidShared { MidLShared L; MidRShared R; };

__device__ void L_path(int bid, const float* __restrict__ lq,
                       const float* __restrict__ cosb, const float* __restrict__ sinb,
                       const float* __restrict__ lk_out, float* __restrict__ Lbuf,
                       MidLShared& sh) {
  const int h = bid / (NF * NB2);
  const int rem = bid % (NF * NB2);
  const int a = rem / NB2, j = rem % NB2;
  const int tid = threadIdx.x;
  for (int idx = tid; idx < NB1 * 32; idx += 256) {
    int i = idx >> 5, mm = idx & 31;
    int srow = a * (NB1 * NB2) + i * NB2 + j;
    const float* xr = lq + (size_t)srow * STRIDE_HD + h * DD;
    float x0 = xr[2 * mm], x1 = xr[2 * mm + 1];
    float co = cosb[srow * 32 + mm], si = sinb[srow * 32 + mm];
    sh.qs[i][2 * mm]     = x0 * co - x1 * si;
    sh.qs[i][2 * mm + 1] = x1 * co + x0 * si;
  }
  for (int idx = tid; idx < FB1 * DD; idx += 256) {
    int r = idx >> 6, d = idx & 63;
    sh.ks[r][d] = lk_out[(size_t)r * STRIDE_HD + h * DD + d];
  }
  __syncthreads();
  for (int t = tid; t < NF * 14 * 14; t += 256) {
    int ff = t / 196, rr = t % 196;
    int it = rr / 14, kt = rr % 14;
    const float4* q0 = (const float4*)sh.qs[2 * it];
    const float4* q1 = (const float4*)sh.qs[2 * it + 1];
    const float4* k0 = (const float4*)sh.ks[ff * NB1 + 2 * kt];
    const float4* k1 = (const float4*)sh.ks[ff * NB1 + 2 * kt + 1];
    float a00 = 0.f, a01 = 0.f, a10 = 0.f, a11 = 0.f;
    #pragma unroll
    for (int d4 = 0; d4 < 16; ++d4) {
      float4 qa = q0[d4], qb = q1[d4], ka = k0[d4], kb = k1[d4];
      a00 += qa.x * ka.x + qa.y * ka.y + qa.z * ka.z + qa.w * ka.w;
      a01 += qa.x * kb.x + qa.y * kb.y + qa.z * kb.z + qa.w * kb.w;
      a10 += qb.x * ka.x + qb.y * ka.y + qb.z * ka.z + qb.w * ka.w;
      a11 += qb.x * kb.x + qb.y * kb.y + qb.z * kb.z + qb.w * kb.w;
    }
    size_t ob = (size_t)bid * (NF * NB1 * NB1) + (size_t)ff * (NB1 * NB1);
    Lbuf[ob + (size_t)(2 * it) * NB1 + 2 * kt]         = a00;
    Lbuf[ob + (size_t)(2 * it) * NB1 + 2 * kt + 1]     = a01;
    Lbuf[ob + (size_t)(2 * it + 1) * NB1 + 2 * kt]     = a10;
    Lbuf[ob + (size_t)(2 * it + 1) * NB1 + 2 * kt + 1] = a11;
  }
}

__device__ void R_path(int bid, const float* __restrict__ rk,
                       const float* __restrict__ cosb, const float* __restrict__ sinb,
                       const float* __restrict__ rq_out, float* __restrict__ Rbuf,
                       MidRShared& sh) {
  const int h = bid / FB1;
  const int fk = bid % FB1;
  const int f = fk / NB1, k = fk % NB1;
  const int tid = threadIdx.x;
  for (int idx = tid; idx < NB2 * 32; idx += 256) {
    int l = idx >> 5, mm = idx & 31;
    int srow = f * (NB1 * NB2) + k * NB2 + l;
    const float* xr = rk + (size_t)srow * STRIDE_HD + h * DD;
    float x0 = xr[2 * mm], x1 = xr[2 * mm + 1];
    float co = cosb[srow * 32 + mm], si = sinb[srow * 32 + mm];
    sh.ks[l][2 * mm]     = x0 * co - x1 * si;
    sh.ks[l][2 * mm + 1] = x1 * co + x0 * si;
  }
  for (int idx = tid; idx < FB2 * DD; idx += 256) {
    int r2 = idx >> 6, d = idx & 63;
    sh.qs[r2][d] = rq_out[(size_t)r2 * STRIDE_HD + h * DD + d];
  }
  __syncthreads();
  for (int t = tid; t < NF * 26 * 26; t += 256) {
    int aa = t / 676, rr = t % 676;
    int jt = rr / 26, lt = rr % 26;
    const float4* q0 = (const float4*)sh.qs[aa * NB2 + 2 * jt];
    const float4* q1 = (const float4*)sh.qs[aa * NB2 + 2 * jt + 1];
    const float4* k0 = (const float4*)sh.ks[2 * lt];
    const float4* k1 = (const float4*)sh.ks[2 * lt + 1];
    float a00 = 0.f, a01 = 0.f, a10 = 0.f, a11 = 0.f;
    #pragma unroll
    for (int d4 = 0; d4 < 16; ++d4) {
      float4 qa = q0[d4], qb = q1[d4], ka = k0[d4], kb = k1[d4];
      a00 += qa.x * ka.x + qa.y * ka.y + qa.z * ka.z + qa.w * ka.w;
      a01 += qa.x * kb.x + qa.y * kb.y + qa.z * kb.z + qa.w * kb.w;
      a10 += qb.x * ka.x + qb.y * ka.y + qb.z * ka.z + qb.w * ka.w;
      a11 += qb.x * kb.x + qb.y * kb.y + qb.z * kb.z + qb.w * kb.w;
    }
    size_t row0 = ((size_t)(h * NF + aa) * NB2 + 2 * jt) * (size_t)(NF * NB1 * NB2);
    size_t row1 = row0 + (size_t)(NF * NB1 * NB2);
    size_t cb = (size_t)fk * NB2 + 2 * lt;
    Rbuf[row0 + cb]     = a00;
    Rbuf[row0 + cb + 1] = a01;
    Rbuf[row1 + cb]     = a10;
    Rbuf[row1 + cb + 1] = a11;
  }
}

__global__ __launch_bounds__(256)
void k_mid(const float* __restrict__ lq, const float* __restrict__ rk,
           const float* __restrict__ cosb, const float* __restrict__ sinb,
           const float* __restrict__ lk_out, const float* __restrict__ rq_out,
           float* __restrict__ Lbuf, float* __restrict__ Rbuf) {
  __shared__ __align__(16) MidShared sh;
  const int bx = blockIdx.x;
  if (bx < 1248) L_path(bx, lq, cosb, sinb, lk_out, Lbuf, sh.L);
  else           R_path(bx - 1248, rk, cosb, sinb, rq_out, Rbuf, sh.R);
}

// ===========================================================================
// MAIN: factorized flash attention. 4 waves = 4 fk-segments; each wave
// computes P once and does 2 MFMAs (both d-halves). No in-loop barriers.
// ===========================================================================
struct MainPro { float Ls2T[2][28][36]; float Rs[56][64]; };
union MainShared { MainPro p; float epil[4][16][64]; };

__global__ __launch_bounds__(256, 4)
void k_main(const float* __restrict__ Lbuf, const float* __restrict__ Rbuf,
            const unsigned short* __restrict__ vb2, float* __restrict__ outp) {
  const int bid0 = blockIdx.x;
  const int bid = (bid0 & 7) * 156 + (bid0 >> 3);   // 1248 = 8*156, XCD-chunked
  const int h = bid / (NF * NB2);
  const int rem = bid % (NF * NB2);
  const int a = rem / NB2, j = rem % NB2;
  const int tid = threadIdx.x;
  const int lane = tid & 63;
  const int w = tid >> 6;

  __shared__ __align__(16) MainShared ms;
  __shared__ float m2s[32], Rmx[FB1], Rmn[FB1], els[4][32];

  const float SC = SCALEF * 1.44269504f;
  for (int idx = tid; idx < NF * NB1 * NB1; idx += 256) {
    int ff = idx / 784, r2 = idx % 784;
    int i = r2 / 28, kk = r2 % 28;
    ms.p.Ls2T[ff][kk][i] = Lbuf[(size_t)bid * (NF * NB1 * NB1) + idx] * SC;
  }
  if (tid < 224) {                                    // zero pad rows i=28..31
    int ff = tid / 112, r2 = tid % 112;
    ms.p.Ls2T[ff][r2 >> 2][28 + (r2 & 3)] = 0.f;
  }
  for (int idx = tid; idx < FB1 * 13; idx += 256) {
    int fk = idx / 13, lc = idx % 13;
    float4 vv = ((const float4*)(Rbuf + (size_t)bid * (NF * NB1 * NB2)))[idx];
    *(float4*)&ms.p.Rs[fk][lc * 4] = vv;
  }
  if (tid >= 252) m2s[tid - 224] = 0.f;               // pad rows 28..31
  __syncthreads();

  if (tid < 224) {                                    // col max/min of R
    int fk = tid >> 2, part = tid & 3;
    float mx = -1e30f, mn = 1e30f;
    for (int l = part * 13; l < part * 13 + 13; ++l) {
      float x = ms.p.Rs[fk][l];
      mx = fmaxf(mx, x); mn = fminf(mn, x);
    }
    mx = fmaxf(mx, __shfl_xor(mx, 1)); mn = fminf(mn, __shfl_xor(mn, 1));
    mx = fmaxf(mx, __shfl_xor(mx, 2)); mn = fminf(mn, __shfl_xor(mn, 2));
    if (part == 0) { Rmx[fk] = mx; Rmn[fk] = mn; }
  }
  __syncthreads();

  if (tid < 224) {                                    // exact row max (log2 units)
    int i = tid >> 3, s = tid & 7;
    float m = -1e30f;
    #pragma unroll
    for (int n = 0; n < 7; ++n) {
      int fk = s + 8 * n;
      int ff = (fk >= NB1) ? 1 : 0, kk = fk - ff * NB1;
      float Lv = ms.p.Ls2T[ff][kk][i];
      m = fmaxf(m, fmaxf(Lv * Rmx[fk], Lv * Rmn[fk]));
    }
    m = fmaxf(m, __shfl_xor(m, 1));
    m = fmaxf(m, __shfl_xor(m, 2));
    m = fmaxf(m, __shfl_xor(m, 4));
    if (s == 0) m2s[i] = m;
  }
  __syncthreads();

  const int row = lane & 31;
  const int hi = lane >> 5;
  const float nm = -m2s[row];
  // vb2 layout: [h][fk][l8][d][li], bf16x8 granule index = fk*512 + l8*64 + d
  const bf16x8* vw = (const bf16x8*)vb2 + (size_t)h * 28672 + hi * 64 + row;

  f32x16 acc0 = {0.f,0.f,0.f,0.f,0.f,0.f,0.f,0.f,0.f,0.f,0.f,0.f,0.f,0.f,0.f,0.f};
  f32x16 acc1 = {0.f,0.f,0.f,0.f,0.f,0.f,0.f,0.f,0.f,0.f,0.f,0.f,0.f,0.f,0.f,0.f};
  float lsum = 0.f;

  for (int t = 0; t < 14; ++t) {
    const int fk = w * 14 + t;
    const float Lv = ms.p.Ls2T[w >> 1][(w & 1) * 14 + t][row];
    const bf16x8* vp = vw + (size_t)fk * 512;
    #pragma unroll
    for (int ks = 0; ks < 4; ++ks) {
      const int k0 = ks * 16 + hi * 8;
      float4 ra = *(const float4*)&ms.p.Rs[fk][k0];
      float4 rb = *(const float4*)&ms.p.Rs[fk][k0 + 4];
      float p0 = EXP2(fmaf(Lv, ra.x, nm));
      float p1 = EXP2(fmaf(Lv, ra.y, nm));
      float p2 = EXP2(fmaf(Lv, ra.z, nm));
      float p3 = EXP2(fmaf(Lv, ra.w, nm));
      float p4 = EXP2(fmaf(Lv, rb.x, nm));
      float p5 = EXP2(fmaf(Lv, rb.y, nm));
      float p6 = EXP2(fmaf(Lv, rb.z, nm));
      float p7 = EXP2(fmaf(Lv, rb.w, nm));
      if (ks == 3) {                                  // l = 48+hi*8+idx; mask l>=52
        if (hi == 0) { p4 = 0.f; p5 = 0.f; p6 = 0.f; p7 = 0.f; }
        else { p0 = 0.f; p1 = 0.f; p2 = 0.f; p3 = 0.f;
               p4 = 0.f; p5 = 0.f; p6 = 0.f; p7 = 0.f; }
      }
      lsum += ((p0 + p1) + (p2 + p3)) + ((p4 + p5) + (p6 + p7));
      union { bf16x8 v8; __hip_bfloat162 h2[4]; } pk;
      pk.h2[0] = __float22bfloat162_rn(make_float2(p0, p1));
      pk.h2[1] = __float22bfloat162_rn(make_float2(p2, p3));
      pk.h2[2] = __float22bfloat162_rn(make_float2(p4, p5));
      pk.h2[3] = __float22bfloat162_rn(make_float2(p6, p7));
      bf16x8 b0 = vp[ks * 128];
      bf16x8 b1 = vp[ks * 128 + 32];
      acc0 = __builtin_amdgcn_mfma_f32_32x32x16_bf16(pk.v8, b0, acc0, 0, 0, 0);
      acc1 = __builtin_amdgcn_mfma_f32_32x32x16_bf16(pk.v8, b1, acc1, 0, 0, 0);
    }
  }

  lsum += __shfl_xor(lsum, 32);
  if (lane < 32) els[w][lane] = lsum;
  __syncthreads();                                     // Rs/Ls2T reads done; els visible

  // epilogue: 2 rounds (d-halves) of 4-segment reduction through LDS
  #pragma unroll
  for (int half = 0; half < 2; ++half) {
    if (half) __syncthreads();
    #pragma unroll
    for (int r = 0; r < 16; ++r)
      ms.epil[w][r][lane] = half ? acc1[r] : acc0[r];
    __syncthreads();
    #pragma unroll
    for (int q = 0; q < 4; ++q) {
      int r = (tid >> 6) + q * 4;
      int elane = tid & 63;
      float val = ms.epil[0][r][elane] + ms.epil[1][r][elane]
                + ms.epil[2][r][elane] + ms.epil[3][r][elane];
      int irow = (r & 3) + 8 * (r >> 2) + 4 * (elane >> 5);
      if (irow < NB1) {
        float li = 1.0f / (els[0][irow] + els[1][irow] + els[2][irow] + els[3][irow]);
        int srow = a * (NB1 * NB2) + irow * NB2 + j;
        int d = half * 32 + (elane & 31);
        outp[(size_t)srow * STRIDE_HD + h * DD + d] = val * li;
      }
    }
  }
}

// ---------------------------------------------------------------------------
extern "C" void kernel_launch(void* const* d_in, const int* in_sizes, int n_in,
                              void* d_out, int out_size, void* d_ws, size_t ws_size,
                              hipStream_t stream) {
  (void)in_sizes; (void)n_in; (void)out_size; (void)ws_size;
  const float* lq   = (const float*)d_in[0];
  const float* lk   = (const float*)d_in[1];
  const float* rq   = (const float*)d_in[2];
  const float* rk   = (const float*)d_in[3];
  const float* v    = (const float*)d_in[4];
  const float* cosb = (const float*)d_in[5];
  const float* sinb = (const float*)d_in[6];
  const float* W_lkq = (const float*)d_in[7];  const float* b_lkq = (const float*)d_in[8];
  const float* W_lkk = (const float*)d_in[9];  const float* b_lkk = (const float*)d_in[10];
  const float* W_lkv = (const float*)d_in[11]; const float* b_lkv = (const float*)d_in[12];
  const float* W_rqq = (const float*)d_in[13]; const float* b_rqq = (const float*)d_in[14];
  const float* W_rqk = (const float*)d_in[15]; const float* b_rqk = (const float*)d_in[16];
  const float* W_rqv = (const float*)d_in[17]; const float* b_rqv = (const float*)d_in[18];

  float* ws = (float*)d_ws;
  float* lk_out = ws;                                               // 56*768
  float* rq_out = lk_out + (size_t)FB1 * STRIDE_HD;                 // 104*768
  float* Lbuf   = rq_out + (size_t)FB2 * STRIDE_HD;                 // 1248*1568
  float* Rbuf   = Lbuf + (size_t)HH * NF * NB2 * (NF * NB1 * NB1);  // 1248*2912
  unsigned short* vb2 =
      (unsigned short*)(Rbuf + (size_t)HH * NF * NB2 * (NF * NB1 * NB2)); // 12*56*8*64*8

  k_front<<<2592, 256, 0, stream>>>(lk, rq, v, cosb, sinb,
      W_lkq, b_lkq, W_lkk, b_lkk, W_lkv, b_lkv,
      W_rqq, b_rqq, W_rqk, b_rqk, W_rqv, b_rqv,
      lk_out, rq_out, vb2);
  k_mid<<<1920, 256, 0, stream>>>(lq, rk, cosb, sinb, lk_out, rq_out, Lbuf, Rbuf);
  k_main<<<1248, 256, 0, stream>>>(Lbuf, Rbuf, vb2, (float*)d_out);
}

// Round 5
// 159.189 us; speedup vs baseline: 1.4209x; 1.2151x over previous
//
#include <hip/hip_runtime.h>
#include <hip/hip_bf16.h>

#define HH 12
#define DD 64
#define NB1 28
#define NB2 52
#define NF 2
#define FB1 56           // NF*NB1
#define FB2 104          // NF*NB2
#define STRIDE_HD 768    // HH*DD
#define SCALEF 0.125f

typedef float f32x4 __attribute__((ext_vector_type(4)));
typedef float f32x16 __attribute__((ext_vector_type(16)));
typedef short bf16x8 __attribute__((ext_vector_type(8)));

#if __has_builtin(__builtin_amdgcn_exp2f)
#define EXP2(x) __builtin_amdgcn_exp2f(x)
#else
#define EXP2(x) __expf((x) * 0.6931471805599453f)
#endif

__device__ __forceinline__ unsigned short f2bf(float x) {
  union { float f; unsigned u; } c; c.f = x;
  unsigned r = c.u + 0x7fffu + ((c.u >> 16) & 1u);
  return (unsigned short)(r >> 16);
}

// ===========================================================================
// k_proj: batched 28-row x 64-out projection + rope, outputs key-grouped.
// path 0: lkk (2912 rows) -> Klg[h][n=f*28+b1][r=b2][d]
// path 1: rqk (2912 rows) -> Krg[h][n=f*52+j ][r=b1][d]
// path 2: lkq (56 q-rows) -> ql[h][n][d]
// path 3: rqq (104 q-rows)-> qr[h][n][d]
// ===========================================================================
__global__ __launch_bounds__(256)
void k_proj(const float* __restrict__ lk, const float* __restrict__ rq,
            const float* __restrict__ cosb, const float* __restrict__ sinb,
            const float* __restrict__ W_lkk, const float* __restrict__ b_lkk,
            const float* __restrict__ W_rqk, const float* __restrict__ b_rqk,
            const float* __restrict__ W_lkq, const float* __restrict__ b_lkq,
            const float* __restrict__ W_rqq, const float* __restrict__ b_rqq,
            float* __restrict__ Klg, float* __restrict__ Krg,
            float* __restrict__ ql, float* __restrict__ qr) {
  __shared__ __align__(16) float Ws[64][68];
  __shared__ __align__(16) float xs[28][68];
  __shared__ int srows[28];
  __shared__ int obase[28];

  const int tid = threadIdx.x;
  int bx = blockIdx.x;
  int path, h, c;
  if (bx < 1248)      { path = 0; h = bx / 104; c = bx % 104; }
  else if (bx < 2496) { path = 1; bx -= 1248; h = bx / 104; c = bx % 104; }
  else if (bx < 2520) { path = 2; bx -= 2496; h = bx / 2;   c = bx % 2; }
  else                { path = 3; bx -= 2520; h = bx / 4;   c = bx % 4; }

  const float* X  = (path == 1 || path == 3) ? rq : lk;
  const float* W  = (path == 0) ? W_lkk : (path == 1) ? W_rqk : (path == 2) ? W_lkq : W_rqq;
  const float* bb = (path == 0) ? b_lkk : (path == 1) ? b_rqk : (path == 2) ? b_lkq : b_rqq;
  float* out      = (path == 0) ? Klg : (path == 1) ? Krg : (path == 2) ? ql : qr;
  const int nrows = (path == 3 && c == 3) ? 20 : 28;

  for (int idx = tid; idx < 4096; idx += 256)
    Ws[idx >> 6][idx & 63] = W[(size_t)h * 4096 + idx];
  if (tid < 28) {
    int rr = tid, s = 0, ob = 0;
    if (path == 0) {
      s = c * 28 + rr;
      int f = s / 1456, rem = s % 1456, b1 = rem / 52, b2 = rem % 52;
      ob = ((h * 56 + f * 28 + b1) * 52 + b2) * 64;
    } else if (path == 1) {
      s = c * 28 + rr;
      int f = s / 1456, rem = s % 1456, b1 = rem / 52, jj = rem % 52;
      ob = ((h * 104 + f * 52 + jj) * 28 + b1) * 64;
    } else if (path == 2) {
      int q = c * 28 + rr;
      s = (q / 28) * 1456 + (q % 28) * 52;
      ob = (h * 56 + q) * 64;
    } else {
      int q = c * 28 + rr;
      if (q < 104) { s = (q / 52) * 1456 + (q % 52); ob = (h * 104 + q) * 64; }
    }
    srows[rr] = s; obase[rr] = ob;
  }
  __syncthreads();
  for (int idx = tid; idx < 1792; idx += 256) {
    int r = idx >> 6, d = idx & 63;
    xs[r][d] = (r < nrows) ? X[(size_t)srows[r] * STRIDE_HD + h * DD + d] : 0.f;
  }
  __syncthreads();

  if (tid < 224) {
    const int it = tid >> 4, kt = tid & 15;  // rows 2it,2it+1; e-pairs (2kt,2kt+1),(2kt+32,2kt+33)
    const float4* x0 = (const float4*)xs[2 * it];
    const float4* x1 = (const float4*)xs[2 * it + 1];
    const float4* w0 = (const float4*)Ws[2 * kt];
    const float4* w1 = (const float4*)Ws[2 * kt + 1];
    const float4* w2 = (const float4*)Ws[2 * kt + 32];
    const float4* w3 = (const float4*)Ws[2 * kt + 33];
    float a00 = 0, a01 = 0, a02 = 0, a03 = 0;
    float a10 = 0, a11 = 0, a12 = 0, a13 = 0;
    #pragma unroll
    for (int d4 = 0; d4 < 16; ++d4) {
      float4 xa = x0[d4], xb = x1[d4];
      float4 wa = w0[d4], wb = w1[d4], wc = w2[d4], wd = w3[d4];
      a00 += xa.x * wa.x + xa.y * wa.y + xa.z * wa.z + xa.w * wa.w;
      a01 += xa.x * wb.x + xa.y * wb.y + xa.z * wb.z + xa.w * wb.w;
      a02 += xa.x * wc.x + xa.y * wc.y + xa.z * wc.z + xa.w * wc.w;
      a03 += xa.x * wd.x + xa.y * wd.y + xa.z * wd.z + xa.w * wd.w;
      a10 += xb.x * wa.x + xb.y * wa.y + xb.z * wa.z + xb.w * wa.w;
      a11 += xb.x * wb.x + xb.y * wb.y + xb.z * wb.z + xb.w * wb.w;
      a12 += xb.x * wc.x + xb.y * wc.y + xb.z * wc.z + xb.w * wc.w;
      a13 += xb.x * wd.x + xb.y * wd.y + xb.z * wd.z + xb.w * wd.w;
    }
    const float bb0 = bb[h * 64 + 2 * kt],      bb1 = bb[h * 64 + 2 * kt + 1];
    const float bb2 = bb[h * 64 + 2 * kt + 32], bb3 = bb[h * 64 + 2 * kt + 33];
    #pragma unroll
    for (int rw = 0; rw < 2; ++rw) {
      int r = 2 * it + rw;
      if (r < nrows) {
        int s = srows[r];
        float co0 = cosb[s * 32 + kt],      si0 = sinb[s * 32 + kt];
        float co1 = cosb[s * 32 + kt + 16], si1 = sinb[s * 32 + kt + 16];
        float v0 = (rw ? a10 : a00) + bb0, v1 = (rw ? a11 : a01) + bb1;
        float v2 = (rw ? a12 : a02) + bb2, v3 = (rw ? a13 : a03) + bb3;
        float* op = out + obase[r];
        *(float2*)(op + 2 * kt)      = make_float2(v0 * co0 - v1 * si0, v1 * co0 + v0 * si0);
        *(float2*)(op + 2 * kt + 32) = make_float2(v2 * co1 - v3 * si1, v3 * co1 + v2 * si1);
      }
    }
  }
}

// ===========================================================================
// k_sv: per-(n,h) tiny SDPA (wide phases) for both paths + V bf16 re-layout
// ===========================================================================
struct SvShared {
  union {
    struct { float qv[64]; float sc[64]; float ps[64]; float ys[64]; float oe[64]; } s;
    float tile[52][68];
  } u;
};

template<int NK, int NG, int GD, int GMUL, int KSTR>
__device__ void sdpa_path(int n, int h, const float* __restrict__ X,
                          const float* __restrict__ Kg, const float* __restrict__ qb,
                          const float* __restrict__ cosb, const float* __restrict__ sinb,
                          const float* __restrict__ Wv, const float* __restrict__ bvv,
                          float* __restrict__ outb, SvShared& sm) {
  const int t = threadIdx.x;
  const int f = n / GD, g = n % GD;
  const int s_base = f * (NB1 * NB2) + g * GMUL;

  if (t < 64) sm.u.s.qv[t] = qb[(size_t)(h * NG + n) * 64 + t];
  __syncthreads();

  if (t < NK * 4) {                 // scores: 4 threads per key
    int r = t >> 2, part = t & 3;
    const float4* kr = (const float4*)(Kg + ((size_t)(h * NG + n) * NK + r) * 64 + part * 16);
    const float4* q4 = (const float4*)(sm.u.s.qv + part * 16);
    float p = 0.f;
    #pragma unroll
    for (int i = 0; i < 4; ++i) {
      float4 kv = kr[i], qv4 = q4[i];
      p += kv.x * qv4.x + kv.y * qv4.y + kv.z * qv4.z + kv.w * qv4.w;
    }
    p += __shfl_xor(p, 1); p += __shfl_xor(p, 2);
    if (part == 0) sm.u.s.sc[r] = p * SCALEF;
  }
  __syncthreads();

  if (t < 64) {                     // softmax over NK
    float v = (t < NK) ? sm.u.s.sc[t] : -1e30f;
    float mx = v;
    for (int o = 32; o; o >>= 1) mx = fmaxf(mx, __shfl_xor(mx, o));
    float e = (t < NK) ? __expf(v - mx) : 0.f;
    float sum = e;
    for (int o = 32; o; o >>= 1) sum += __shfl_xor(sum, o);
    sm.u.s.ps[t] = (t < NK) ? e / sum : 0.f;
  }
  __syncthreads();

  {                                 // pool y = sum_r p_r x_r  (4 threads per dim)
    int d = t >> 2, g4 = t & 3;
    constexpr int RPG = NK / 4;
    float yp = 0.f;
    #pragma unroll 4
    for (int rr = 0; rr < RPG; ++rr) {
      int r = g4 * RPG + rr;
      yp += sm.u.s.ps[r] * X[(size_t)(s_base + r * KSTR) * STRIDE_HD + h * DD + d];
    }
    yp += __shfl_xor(yp, 1); yp += __shfl_xor(yp, 2);
    if (g4 == 0) sm.u.s.ys[d] = yp;
  }
  __syncthreads();

  {                                 // out = Wv y + bv  (4 threads per out)
    int e = t >> 2, part = t & 3;
    const float4* wr = (const float4*)(Wv + (size_t)h * 4096 + e * 64 + part * 16);
    const float4* y4 = (const float4*)(sm.u.s.ys + part * 16);
    float p = 0.f;
    #pragma unroll
    for (int i = 0; i < 4; ++i) {
      float4 wv = wr[i], yv = y4[i];
      p += wv.x * yv.x + wv.y * yv.y + wv.z * yv.z + wv.w * yv.w;
    }
    p += __shfl_xor(p, 1); p += __shfl_xor(p, 2);
    if (part == 0) sm.u.s.oe[e] = p + bvv[h * 64 + e];
  }
  __syncthreads();

  if (t < 32) {                     // output rope + store
    float co = cosb[s_base * 32 + t], si = sinb[s_base * 32 + t];
    float o0 = sm.u.s.oe[2 * t], o1 = sm.u.s.oe[2 * t + 1];
    outb[(size_t)n * STRIDE_HD + h * DD + 2 * t]     = o0 * co - o1 * si;
    outb[(size_t)n * STRIDE_HD + h * DD + 2 * t + 1] = o1 * co + o0 * si;
  }
}

// v (S,H,D) f32 -> vb2[h][fk][l8][d][li] bf16 (l = l8*8+li, l>=52 zero)
__device__ void vb_path(int fk, int h, const float* __restrict__ v,
                        unsigned short* __restrict__ vb2, SvShared& sm) {
  const int tid = threadIdx.x;
  for (int idx = tid; idx < NB2 * DD; idx += 256) {
    int l = idx >> 6, d = idx & 63;
    sm.u.tile[l][d] = v[(size_t)(fk * NB2 + l) * STRIDE_HD + h * DD + d];
  }
  __syncthreads();
  for (int idx = tid; idx < 512; idx += 256) {
    int l8 = idx >> 6, d = idx & 63;
    unsigned short tmp[8];
    #pragma unroll
    for (int li = 0; li < 8; ++li) {
      int l = l8 * 8 + li;
      tmp[li] = (l < NB2) ? f2bf(sm.u.tile[l][d]) : (unsigned short)0;
    }
    bf16x8* dst = (bf16x8*)(vb2 + (((size_t)(h * FB1 + fk) * 8 + l8) * 64 + d) * 8);
    *dst = *(bf16x8*)tmp;
  }
}

__global__ __launch_bounds__(256)
void k_sv(const float* __restrict__ lk, const float* __restrict__ rq,
          const float* __restrict__ v,
          const float* __restrict__ cosb, const float* __restrict__ sinb,
          const float* __restrict__ Klg, const float* __restrict__ Krg,
          const float* __restrict__ ql, const float* __restrict__ qr,
          const float* __restrict__ W_lkv, const float* __restrict__ b_lkv,
          const float* __restrict__ W_rqv, const float* __restrict__ b_rqv,
          float* __restrict__ lk_out, float* __restrict__ rq_out,
          unsigned short* __restrict__ vb2) {
  __shared__ SvShared sm;
  const int bx = blockIdx.x;
  if (bx < 672) {
    sdpa_path<52, 56, 28, 52, 1>(bx % 56, bx / 56, lk, Klg, ql, cosb, sinb,
                                 W_lkv, b_lkv, lk_out, sm);
  } else if (bx < 1920) {
    int id = bx - 672;
    sdpa_path<28, 104, 52, 1, 52>(id % 104, id / 104, rq, Krg, qr, cosb, sinb,
                                  W_rqv, b_rqv, rq_out, sm);
  } else {
    int id = bx - 1920;
    vb_path(id % 56, id / 56, v, vb2, sm);
  }
}

// ===========================================================================
// MID: fused L and R contractions (both 2x2 register-blocked)
// ===========================================================================
struct MidLShared { float qs[NB1][68]; float ks[FB1][68]; };
struct MidRShared { float ks[NB2][68]; float qs[FB2][68]; };
union MidShared { MidLShared L; MidRShared R; };

__device__ void L_path(int bid, const float* __restrict__ lq,
                       const float* __restrict__ cosb, const float* __restrict__ sinb,
                       const float* __restrict__ lk_out, float* __restrict__ Lbuf,
                       MidLShared& sh) {
  const int h = bid / (NF * NB2);
  const int rem = bid % (NF * NB2);
  const int a = rem / NB2, j = rem % NB2;
  const int tid = threadIdx.x;
  for (int idx = tid; idx < NB1 * 32; idx += 256) {
    int i = idx >> 5, mm = idx & 31;
    int srow = a * (NB1 * NB2) + i * NB2 + j;
    const float* xr = lq + (size_t)srow * STRIDE_HD + h * DD;
    float x0 = xr[2 * mm], x1 = xr[2 * mm + 1];
    float co = cosb[srow * 32 + mm], si = sinb[srow * 32 + mm];
    sh.qs[i][2 * mm]     = x0 * co - x1 * si;
    sh.qs[i][2 * mm + 1] = x1 * co + x0 * si;
  }
  for (int idx = tid; idx < FB1 * DD; idx += 256) {
    int r = idx >> 6, d = idx & 63;
    sh.ks[r][d] = lk_out[(size_t)r * STRIDE_HD + h * DD + d];
  }
  __syncthreads();
  for (int t = tid; t < NF * 14 * 14; t += 256) {
    int ff = t / 196, rr = t % 196;
    int it = rr / 14, kt = rr % 14;
    const float4* q0 = (const float4*)sh.qs[2 * it];
    const float4* q1 = (const float4*)sh.qs[2 * it + 1];
    const float4* k0 = (const float4*)sh.ks[ff * NB1 + 2 * kt];
    const float4* k1 = (const float4*)sh.ks[ff * NB1 + 2 * kt + 1];
    float a00 = 0.f, a01 = 0.f, a10 = 0.f, a11 = 0.f;
    #pragma unroll
    for (int d4 = 0; d4 < 16; ++d4) {
      float4 qa = q0[d4], qb = q1[d4], ka = k0[d4], kb = k1[d4];
      a00 += qa.x * ka.x + qa.y * ka.y + qa.z * ka.z + qa.w * ka.w;
      a01 += qa.x * kb.x + qa.y * kb.y + qa.z * kb.z + qa.w * kb.w;
      a10 += qb.x * ka.x + qb.y * ka.y + qb.z * ka.z + qb.w * ka.w;
      a11 += qb.x * kb.x + qb.y * kb.y + qb.z * kb.z + qb.w * kb.w;
    }
    size_t ob = (size_t)bid * (NF * NB1 * NB1) + (size_t)ff * (NB1 * NB1);
    Lbuf[ob + (size_t)(2 * it) * NB1 + 2 * kt]         = a00;
    Lbuf[ob + (size_t)(2 * it) * NB1 + 2 * kt + 1]     = a01;
    Lbuf[ob + (size_t)(2 * it + 1) * NB1 + 2 * kt]     = a10;
    Lbuf[ob + (size_t)(2 * it + 1) * NB1 + 2 * kt + 1] = a11;
  }
}

__device__ void R_path(int bid, const float* __restrict__ rk,
                       const float* __restrict__ cosb, const float* __restrict__ sinb,
                       const float* __restrict__ rq_out, float* __restrict__ Rbuf,
                       MidRShared& sh) {
  const int h = bid / FB1;
  const int fk = bid % FB1;
  const int f = fk / NB1, k = fk % NB1;
  const int tid = threadIdx.x;
  for (int idx = tid; idx < NB2 * 32; idx += 256) {
    int l = idx >> 5, mm = idx & 31;
    int srow = f * (NB1 * NB2) + k * NB2 + l;
    const float* xr = rk + (size_t)srow * STRIDE_HD + h * DD;
    float x0 = xr[2 * mm], x1 = xr[2 * mm + 1];
    float co = cosb[srow * 32 + mm], si = sinb[srow * 32 + mm];
    sh.ks[l][2 * mm]     = x0 * co - x1 * si;
    sh.ks[l][2 * mm + 1] = x1 * co + x0 * si;
  }
  for (int idx = tid; idx < FB2 * DD; idx += 256) {
    int r2 = idx >> 6, d = idx & 63;
    sh.qs[r2][d] = rq_out[(size_t)r2 * STRIDE_HD + h * DD + d];
  }
  __syncthreads();
  for (int t = tid; t < NF * 26 * 26; t += 256) {
    int aa = t / 676, rr = t % 676;
    int jt = rr / 26, lt = rr % 26;
    const float4* q0 = (const float4*)sh.qs[aa * NB2 + 2 * jt];
    const float4* q1 = (const float4*)sh.qs[aa * NB2 + 2 * jt + 1];
    const float4* k0 = (const float4*)sh.ks[2 * lt];
    const float4* k1 = (const float4*)sh.ks[2 * lt + 1];
    float a00 = 0.f, a01 = 0.f, a10 = 0.f, a11 = 0.f;
    #pragma unroll
    for (int d4 = 0; d4 < 16; ++d4) {
      float4 qa = q0[d4], qb = q1[d4], ka = k0[d4], kb = k1[d4];
      a00 += qa.x * ka.x + qa.y * ka.y + qa.z * ka.z + qa.w * ka.w;
      a01 += qa.x * kb.x + qa.y * kb.y + qa.z * kb.z + qa.w * kb.w;
      a10 += qb.x * ka.x + qb.y * ka.y + qb.z * ka.z + qb.w * ka.w;
      a11 += qb.x * kb.x + qb.y * kb.y + qb.z * kb.z + qb.w * kb.w;
    }
    size_t row0 = ((size_t)(h * NF + aa) * NB2 + 2 * jt) * (size_t)(NF * NB1 * NB2);
    size_t row1 = row0 + (size_t)(NF * NB1 * NB2);
    size_t cb = (size_t)fk * NB2 + 2 * lt;
    Rbuf[row0 + cb]     = a00;
    Rbuf[row0 + cb + 1] = a01;
    Rbuf[row1 + cb]     = a10;
    Rbuf[row1 + cb + 1] = a11;
  }
}

__global__ __launch_bounds__(256)
void k_mid(const float* __restrict__ lq, const float* __restrict__ rk,
           const float* __restrict__ cosb, const float* __restrict__ sinb,
           const float* __restrict__ lk_out, const float* __restrict__ rq_out,
           float* __restrict__ Lbuf, float* __restrict__ Rbuf) {
  __shared__ __align__(16) MidShared sh;
  const int bx = blockIdx.x;
  if (bx < 1248) L_path(bx, lq, cosb, sinb, lk_out, Lbuf, sh.L);
  else           R_path(bx - 1248, rk, cosb, sinb, rq_out, Rbuf, sh.R);
}

// ===========================================================================
// MAIN: factorized flash attention. 4 waves = 4 fk-segments; each wave
// computes P once and does 2 MFMAs (both d-halves). No in-loop barriers.
// ===========================================================================
struct MainPro { float Ls2T[2][28][36]; float Rs[56][64]; };
union MainShared { MainPro p; float epil[4][16][64]; };

__global__ __launch_bounds__(256, 4)
void k_main(const float* __restrict__ Lbuf, const float* __restrict__ Rbuf,
            const unsigned short* __restrict__ vb2, float* __restrict__ outp) {
  const int bid0 = blockIdx.x;
  const int bid = (bid0 & 7) * 156 + (bid0 >> 3);   // 1248 = 8*156, XCD-chunked
  const int h = bid / (NF * NB2);
  const int rem = bid % (NF * NB2);
  const int a = rem / NB2, j = rem % NB2;
  const int tid = threadIdx.x;
  const int lane = tid & 63;
  const int w = tid >> 6;

  __shared__ __align__(16) MainShared ms;
  __shared__ float m2s[32], Rmx[FB1], Rmn[FB1], els[4][32];

  const float SC = SCALEF * 1.44269504f;
  for (int idx = tid; idx < NF * NB1 * NB1; idx += 256) {
    int ff = idx / 784, r2 = idx % 784;
    int i = r2 / 28, kk = r2 % 28;
    ms.p.Ls2T[ff][kk][i] = Lbuf[(size_t)bid * (NF * NB1 * NB1) + idx] * SC;
  }
  if (tid < 224) {                                    // zero pad rows i=28..31
    int ff = tid / 112, r2 = tid % 112;
    ms.p.Ls2T[ff][r2 >> 2][28 + (r2 & 3)] = 0.f;
  }
  for (int idx = tid; idx < FB1 * 13; idx += 256) {
    int fk = idx / 13, lc = idx % 13;
    float4 vv = ((const float4*)(Rbuf + (size_t)bid * (NF * NB1 * NB2)))[idx];
    *(float4*)&ms.p.Rs[fk][lc * 4] = vv;
  }
  if (tid >= 252) m2s[tid - 224] = 0.f;               // pad rows 28..31
  __syncthreads();

  if (tid < 224) {                                    // col max/min of R
    int fk = tid >> 2, part = tid & 3;
    float mx = -1e30f, mn = 1e30f;
    for (int l = part * 13; l < part * 13 + 13; ++l) {
      float x = ms.p.Rs[fk][l];
      mx = fmaxf(mx, x); mn = fminf(mn, x);
    }
    mx = fmaxf(mx, __shfl_xor(mx, 1)); mn = fminf(mn, __shfl_xor(mn, 1));
    mx = fmaxf(mx, __shfl_xor(mx, 2)); mn = fminf(mn, __shfl_xor(mn, 2));
    if (part == 0) { Rmx[fk] = mx; Rmn[fk] = mn; }
  }
  __syncthreads();

  if (tid < 224) {                                    // exact row max (log2 units)
    int i = tid >> 3, s = tid & 7;
    float m = -1e30f;
    #pragma unroll
    for (int n = 0; n < 7; ++n) {
      int fk = s + 8 * n;
      int ff = (fk >= NB1) ? 1 : 0, kk = fk - ff * NB1;
      float Lv = ms.p.Ls2T[ff][kk][i];
      m = fmaxf(m, fmaxf(Lv * Rmx[fk], Lv * Rmn[fk]));
    }
    m = fmaxf(m, __shfl_xor(m, 1));
    m = fmaxf(m, __shfl_xor(m, 2));
    m = fmaxf(m, __shfl_xor(m, 4));
    if (s == 0) m2s[i] = m;
  }
  __syncthreads();

  const int row = lane & 31;
  const int hi = lane >> 5;
  const float nm = -m2s[row];
  // vb2 layout: [h][fk][l8][d][li], bf16x8 granule index = fk*512 + l8*64 + d
  const bf16x8* vw = (const bf16x8*)vb2 + (size_t)h * 28672 + hi * 64 + row;

  f32x16 acc0 = {0.f,0.f,0.f,0.f,0.f,0.f,0.f,0.f,0.f,0.f,0.f,0.f,0.f,0.f,0.f,0.f};
  f32x16 acc1 = {0.f,0.f,0.f,0.f,0.f,0.f,0.f,0.f,0.f,0.f,0.f,0.f,0.f,0.f,0.f,0.f};
  float lsum = 0.f;

  for (int t = 0; t < 14; ++t) {
    const int fk = w * 14 + t;
    const float Lv = ms.p.Ls2T[w >> 1][(w & 1) * 14 + t][row];
    const bf16x8* vp = vw + (size_t)fk * 512;
    #pragma unroll
    for (int ks = 0; ks < 4; ++ks) {
      const int k0 = ks * 16 + hi * 8;
      float4 ra = *(const float4*)&ms.p.Rs[fk][k0];
      float4 rb = *(const float4*)&ms.p.Rs[fk][k0 + 4];
      float p0 = EXP2(fmaf(Lv, ra.x, nm));
      float p1 = EXP2(fmaf(Lv, ra.y, nm));
      float p2 = EXP2(fmaf(Lv, ra.z, nm));
      float p3 = EXP2(fmaf(Lv, ra.w, nm));
      float p4 = EXP2(fmaf(Lv, rb.x, nm));
      float p5 = EXP2(fmaf(Lv, rb.y, nm));
      float p6 = EXP2(fmaf(Lv, rb.z, nm));
      float p7 = EXP2(fmaf(Lv, rb.w, nm));
      if (ks == 3) {                                  // l = 48+hi*8+idx; mask l>=52
        if (hi == 0) { p4 = 0.f; p5 = 0.f; p6 = 0.f; p7 = 0.f; }
        else { p0 = 0.f; p1 = 0.f; p2 = 0.f; p3 = 0.f;
               p4 = 0.f; p5 = 0.f; p6 = 0.f; p7 = 0.f; }
      }
      lsum += ((p0 + p1) + (p2 + p3)) + ((p4 + p5) + (p6 + p7));
      union { bf16x8 v8; __hip_bfloat162 h2[4]; } pk;
      pk.h2[0] = __float22bfloat162_rn(make_float2(p0, p1));
      pk.h2[1] = __float22bfloat162_rn(make_float2(p2, p3));
      pk.h2[2] = __float22bfloat162_rn(make_float2(p4, p5));
      pk.h2[3] = __float22bfloat162_rn(make_float2(p6, p7));
      bf16x8 b0 = vp[ks * 128];
      bf16x8 b1 = vp[ks * 128 + 32];
      acc0 = __builtin_amdgcn_mfma_f32_32x32x16_bf16(pk.v8, b0, acc0, 0, 0, 0);
      acc1 = __builtin_amdgcn_mfma_f32_32x32x16_bf16(pk.v8, b1, acc1, 0, 0, 0);
    }
  }

  lsum += __shfl_xor(lsum, 32);
  if (lane < 32) els[w][lane] = lsum;
  __syncthreads();                                     // Rs/Ls2T reads done; els visible

  // epilogue: 2 rounds (d-halves) of 4-segment reduction through LDS
  #pragma unroll
  for (int half = 0; half < 2; ++half) {
    if (half) __syncthreads();
    #pragma unroll
    for (int r = 0; r < 16; ++r)
      ms.epil[w][r][lane] = half ? acc1[r] : acc0[r];
    __syncthreads();
    #pragma unroll
    for (int q = 0; q < 4; ++q) {
      int r = (tid >> 6) + q * 4;
      int elane = tid & 63;
      float val = ms.epil[0][r][elane] + ms.epil[1][r][elane]
                + ms.epil[2][r][elane] + ms.epil[3][r][elane];
      int irow = (r & 3) + 8 * (r >> 2) + 4 * (elane >> 5);
      if (irow < NB1) {
        float li = 1.0f / (els[0][irow] + els[1][irow] + els[2][irow] + els[3][irow]);
        int srow = a * (NB1 * NB2) + irow * NB2 + j;
        int d = half * 32 + (elane & 31);
        outp[(size_t)srow * STRIDE_HD + h * DD + d] = val * li;
      }
    }
  }
}

// ---------------------------------------------------------------------------
extern "C" void kernel_launch(void* const* d_in, const int* in_sizes, int n_in,
                              void* d_out, int out_size, void* d_ws, size_t ws_size,
                              hipStream_t stream) {
  (void)in_sizes; (void)n_in; (void)out_size; (void)ws_size;
  const float* lq   = (const float*)d_in[0];
  const float* lk   = (const float*)d_in[1];
  const float* rq   = (const float*)d_in[2];
  const float* rk   = (const float*)d_in[3];
  const float* v    = (const float*)d_in[4];
  const float* cosb = (const float*)d_in[5];
  const float* sinb = (const float*)d_in[6];
  const float* W_lkq = (const float*)d_in[7];  const float* b_lkq = (const float*)d_in[8];
  const float* W_lkk = (const float*)d_in[9];  const float* b_lkk = (const float*)d_in[10];
  const float* W_lkv = (const float*)d_in[11]; const float* b_lkv = (const float*)d_in[12];
  const float* W_rqq = (const float*)d_in[13]; const float* b_rqq = (const float*)d_in[14];
  const float* W_rqk = (const float*)d_in[15]; const float* b_rqk = (const float*)d_in[16];
  const float* W_rqv = (const float*)d_in[17]; const float* b_rqv = (const float*)d_in[18];

  float* ws = (float*)d_ws;
  float* lk_out = ws;                                   // 43008
  float* rq_out = ws + 43008;                           // 79872
  float* Lbuf   = ws + 122880;                          // 1956864
  float* Rbuf   = ws + 2079744;                         // 3634176
  unsigned short* vb2 = (unsigned short*)(ws + 5713920);// 2752512 shorts
  float* ql     = ws + 7090176;                         // 43008
  float* qr     = ws + 7133184;                         // 79872
  // Klg/Krg alias the Lbuf/Rbuf space (dead before k_mid writes them)
  float* Klg = Lbuf;                                    // 2236416
  float* Krg = Lbuf + 2236416;                          // 2236416 (ends < Rbuf end)

  k_proj<<<2568, 256, 0, stream>>>(lk, rq, cosb, sinb,
      W_lkk, b_lkk, W_rqk, b_rqk, W_lkq, b_lkq, W_rqq, b_rqq,
      Klg, Krg, ql, qr);
  k_sv<<<2592, 256, 0, stream>>>(lk, rq, v, cosb, sinb, Klg, Krg, ql, qr,
      W_lkv, b_lkv, W_rqv, b_rqv, lk_out, rq_out, vb2);
  k_mid<<<1920, 256, 0, stream>>>(lq, rk, cosb, sinb, lk_out, rq_out, Lbuf, Rbuf);
  k_main<<<1248, 256, 0, stream>>>(Lbuf, Rbuf, vb2, (float*)d_out);
}

// Round 6
// 111.377 us; speedup vs baseline: 2.0309x; 1.4293x over previous
//
#include <hip/hip_runtime.h>
#include <hip/hip_bf16.h>

#define HH 12
#define DD 64
#define NB1 28
#define NB2 52
#define NF 2
#define FB1 56           // NF*NB1
#define FB2 104          // NF*NB2
#define STRIDE_HD 768    // HH*DD
#define SCALEF 0.125f

typedef float f32x4 __attribute__((ext_vector_type(4)));
typedef float f32x16 __attribute__((ext_vector_type(16)));
typedef short bf16x8 __attribute__((ext_vector_type(8)));

#if __has_builtin(__builtin_amdgcn_exp2f)
#define EXP2(x) __builtin_amdgcn_exp2f(x)
#else
#define EXP2(x) __expf((x) * 0.6931471805599453f)
#endif

__device__ __forceinline__ unsigned short f2bf(float x) {
  union { float f; unsigned u; } c; c.f = x;
  unsigned r = c.u + 0x7fffu + ((c.u >> 16) & 1u);
  return (unsigned short)(r >> 16);
}

// ===========================================================================
// k_proj: 64-row x 64-out projection tiles + rope, outputs key-grouped.
// Wt (transposed W) in LDS -> conflict-free inner reads; 4x4 register tiles;
// 256 tiles = 256 threads; __launch_bounds__(256,4) caps VGPR for occupancy.
// blocks: path0 (lkk) 12h x 46c | path1 (rqk) 12h x 46c | path2 (lkq) 12h
//         | path3 (rqq) 12h x 2c
// ===========================================================================
__global__ __launch_bounds__(256, 4)
void k_proj(const float* __restrict__ lk, const float* __restrict__ rq,
            const float* __restrict__ cosb, const float* __restrict__ sinb,
            const float* __restrict__ W_lkk, const float* __restrict__ b_lkk,
            const float* __restrict__ W_rqk, const float* __restrict__ b_rqk,
            const float* __restrict__ W_lkq, const float* __restrict__ b_lkq,
            const float* __restrict__ W_rqq, const float* __restrict__ b_rqq,
            float* __restrict__ Klg, float* __restrict__ Krg,
            float* __restrict__ ql, float* __restrict__ qr) {
  __shared__ __align__(16) float Wt[64][68];   // [d][e]
  __shared__ __align__(16) float xs[64][68];   // [r][d]
  __shared__ int srows[64];
  __shared__ int obase[64];

  const int tid = threadIdx.x;
  int bx = blockIdx.x;
  int path, h, c;
  if (bx < 552)       { path = 0; h = bx / 46; c = bx % 46; }
  else if (bx < 1104) { path = 1; bx -= 552;  h = bx / 46; c = bx % 46; }
  else if (bx < 1116) { path = 2; h = bx - 1104; c = 0; }
  else                { path = 3; bx -= 1116; h = bx >> 1; c = bx & 1; }

  const float* X  = (path == 1 || path == 3) ? rq : lk;
  const float* W  = (path == 0) ? W_lkk : (path == 1) ? W_rqk : (path == 2) ? W_lkq : W_rqq;
  const float* bb = (path == 0) ? b_lkk : (path == 1) ? b_rqk : (path == 2) ? b_lkq : b_rqq;
  float* out      = (path == 0) ? Klg : (path == 1) ? Krg : (path == 2) ? ql : qr;
  const int nrows = (path == 0 || path == 1) ? ((c == 45) ? 32 : 64)
                   : (path == 2) ? 56 : ((c == 1) ? 40 : 64);

  // stage W transposed: Wt[d][e] = W[h][e][d]
  for (int idx = tid; idx < 4096; idx += 256)
    Wt[idx & 63][idx >> 6] = W[(size_t)h * 4096 + idx];
  if (tid < 64) {
    int rr = tid, s = 0, ob = 0;
    if (rr < nrows) {
      if (path == 0) {
        s = c * 64 + rr;
        int f = s / 1456, rem = s % 1456, b1 = rem / 52, b2 = rem % 52;
        ob = ((h * 56 + f * 28 + b1) * 52 + b2) * 64;
      } else if (path == 1) {
        s = c * 64 + rr;
        int f = s / 1456, rem = s % 1456, b1 = rem / 52, jj = rem % 52;
        ob = ((h * 104 + f * 52 + jj) * 28 + b1) * 64;
      } else if (path == 2) {
        int q = rr;
        s = (q / 28) * 1456 + (q % 28) * 52;
        ob = (h * 56 + q) * 64;
      } else {
        int q = c * 64 + rr;
        s = (q / 52) * 1456 + (q % 52);
        ob = (h * 104 + q) * 64;
      }
    }
    srows[rr] = s; obase[rr] = ob;
  }
  __syncthreads();
  for (int idx = tid; idx < 4096; idx += 256) {
    int r = idx >> 6, d = idx & 63;
    xs[r][d] = X[(size_t)srows[r] * STRIDE_HD + h * DD + d];
  }
  __syncthreads();

  const int it = tid >> 4, kt = tid & 15;   // rows 4it.., outs 4kt..
  f32x4 acc0 = {0,0,0,0}, acc1 = {0,0,0,0}, acc2 = {0,0,0,0}, acc3 = {0,0,0,0};
  #pragma unroll 4
  for (int d4 = 0; d4 < 16; ++d4) {
    f32x4 x0 = *(const f32x4*)&xs[4 * it][4 * d4];
    f32x4 x1 = *(const f32x4*)&xs[4 * it + 1][4 * d4];
    f32x4 x2 = *(const f32x4*)&xs[4 * it + 2][4 * d4];
    f32x4 x3 = *(const f32x4*)&xs[4 * it + 3][4 * d4];
    #pragma unroll
    for (int dd = 0; dd < 4; ++dd) {
      f32x4 wv = *(const f32x4*)&Wt[4 * d4 + dd][4 * kt];
      acc0 += x0[dd] * wv;
      acc1 += x1[dd] * wv;
      acc2 += x2[dd] * wv;
      acc3 += x3[dd] * wv;
    }
  }

  // bias + rope + store (pairs (4kt,4kt+1),(4kt+2,4kt+3) -> m = 2kt, 2kt+1)
  f32x4 bv;
  bv[0] = bb[h * 64 + 4 * kt];     bv[1] = bb[h * 64 + 4 * kt + 1];
  bv[2] = bb[h * 64 + 4 * kt + 2]; bv[3] = bb[h * 64 + 4 * kt + 3];
  #pragma unroll
  for (int rr = 0; rr < 4; ++rr) {
    int row = 4 * it + rr;
    if (row < nrows) {
      f32x4 o = (rr == 0) ? acc0 : (rr == 1) ? acc1 : (rr == 2) ? acc2 : acc3;
      o += bv;
      int s = srows[row];
      float c0 = cosb[s * 32 + 2 * kt],     s0 = sinb[s * 32 + 2 * kt];
      float c1 = cosb[s * 32 + 2 * kt + 1], s1 = sinb[s * 32 + 2 * kt + 1];
      f32x4 res;
      res[0] = o[0] * c0 - o[1] * s0;
      res[1] = o[1] * c0 + o[0] * s0;
      res[2] = o[2] * c1 - o[3] * s1;
      res[3] = o[3] * c1 + o[2] * s1;
      *(f32x4*)(out + obase[row] + 4 * kt) = res;
    }
  }
}

// ===========================================================================
// k_sv: per-(n,h) tiny SDPA (wide phases) for both paths + V bf16 re-layout
// ===========================================================================
struct SvShared {
  union {
    struct { float qv[64]; float sc[64]; float ps[64]; float ys[64]; float oe[64]; } s;
    float tile[52][68];
  } u;
};

template<int NK, int NG, int GD, int GMUL, int KSTR>
__device__ void sdpa_path(int n, int h, const float* __restrict__ X,
                          const float* __restrict__ Kg, const float* __restrict__ qb,
                          const float* __restrict__ cosb, const float* __restrict__ sinb,
                          const float* __restrict__ Wv, const float* __restrict__ bvv,
                          float* __restrict__ outb, SvShared& sm) {
  const int t = threadIdx.x;
  const int f = n / GD, g = n % GD;
  const int s_base = f * (NB1 * NB2) + g * GMUL;

  if (t < 64) sm.u.s.qv[t] = qb[(size_t)(h * NG + n) * 64 + t];
  __syncthreads();

  if (t < NK * 4) {                 // scores: 4 threads per key
    int r = t >> 2, part = t & 3;
    const float4* kr = (const float4*)(Kg + ((size_t)(h * NG + n) * NK + r) * 64 + part * 16);
    const float4* q4 = (const float4*)(sm.u.s.qv + part * 16);
    float p = 0.f;
    #pragma unroll
    for (int i = 0; i < 4; ++i) {
      float4 kv = kr[i], qv4 = q4[i];
      p += kv.x * qv4.x + kv.y * qv4.y + kv.z * qv4.z + kv.w * qv4.w;
    }
    p += __shfl_xor(p, 1); p += __shfl_xor(p, 2);
    if (part == 0) sm.u.s.sc[r] = p * SCALEF;
  }
  __syncthreads();

  if (t < 64) {                     // softmax over NK
    float v = (t < NK) ? sm.u.s.sc[t] : -1e30f;
    float mx = v;
    for (int o = 32; o; o >>= 1) mx = fmaxf(mx, __shfl_xor(mx, o));
    float e = (t < NK) ? __expf(v - mx) : 0.f;
    float sum = e;
    for (int o = 32; o; o >>= 1) sum += __shfl_xor(sum, o);
    sm.u.s.ps[t] = (t < NK) ? e / sum : 0.f;
  }
  __syncthreads();

  {                                 // pool y = sum_r p_r x_r  (4 threads per dim)
    int d = t >> 2, g4 = t & 3;
    constexpr int RPG = NK / 4;
    float yp = 0.f;
    #pragma unroll 4
    for (int rr = 0; rr < RPG; ++rr) {
      int r = g4 * RPG + rr;
      yp += sm.u.s.ps[r] * X[(size_t)(s_base + r * KSTR) * STRIDE_HD + h * DD + d];
    }
    yp += __shfl_xor(yp, 1); yp += __shfl_xor(yp, 2);
    if (g4 == 0) sm.u.s.ys[d] = yp;
  }
  __syncthreads();

  {                                 // out = Wv y + bv  (4 threads per out)
    int e = t >> 2, part = t & 3;
    const float4* wr = (const float4*)(Wv + (size_t)h * 4096 + e * 64 + part * 16);
    const float4* y4 = (const float4*)(sm.u.s.ys + part * 16);
    float p = 0.f;
    #pragma unroll
    for (int i = 0; i < 4; ++i) {
      float4 wv = wr[i], yv = y4[i];
      p += wv.x * yv.x + wv.y * yv.y + wv.z * yv.z + wv.w * yv.w;
    }
    p += __shfl_xor(p, 1); p += __shfl_xor(p, 2);
    if (part == 0) sm.u.s.oe[e] = p + bvv[h * 64 + e];
  }
  __syncthreads();

  if (t < 32) {                     // output rope + store
    float co = cosb[s_base * 32 + t], si = sinb[s_base * 32 + t];
    float o0 = sm.u.s.oe[2 * t], o1 = sm.u.s.oe[2 * t + 1];
    outb[(size_t)n * STRIDE_HD + h * DD + 2 * t]     = o0 * co - o1 * si;
    outb[(size_t)n * STRIDE_HD + h * DD + 2 * t + 1] = o1 * co + o0 * si;
  }
}

// v (S,H,D) f32 -> vb2[h][fk][l8][d][li] bf16 (l = l8*8+li, l>=52 zero)
__device__ void vb_path(int fk, int h, const float* __restrict__ v,
                        unsigned short* __restrict__ vb2, SvShared& sm) {
  const int tid = threadIdx.x;
  for (int idx = tid; idx < NB2 * DD; idx += 256) {
    int l = idx >> 6, d = idx & 63;
    sm.u.tile[l][d] = v[(size_t)(fk * NB2 + l) * STRIDE_HD + h * DD + d];
  }
  __syncthreads();
  for (int idx = tid; idx < 512; idx += 256) {
    int l8 = idx >> 6, d = idx & 63;
    unsigned short tmp[8];
    #pragma unroll
    for (int li = 0; li < 8; ++li) {
      int l = l8 * 8 + li;
      tmp[li] = (l < NB2) ? f2bf(sm.u.tile[l][d]) : (unsigned short)0;
    }
    bf16x8* dst = (bf16x8*)(vb2 + (((size_t)(h * FB1 + fk) * 8 + l8) * 64 + d) * 8);
    *dst = *(bf16x8*)tmp;
  }
}

__global__ __launch_bounds__(256)
void k_sv(const float* __restrict__ lk, const float* __restrict__ rq,
          const float* __restrict__ v,
          const float* __restrict__ cosb, const float* __restrict__ sinb,
          const float* __restrict__ Klg, const float* __restrict__ Krg,
          const float* __restrict__ ql, const float* __restrict__ qr,
          const float* __restrict__ W_lkv, const float* __restrict__ b_lkv,
          const float* __restrict__ W_rqv, const float* __restrict__ b_rqv,
          float* __restrict__ lk_out, float* __restrict__ rq_out,
          unsigned short* __restrict__ vb2) {
  __shared__ SvShared sm;
  const int bx = blockIdx.x;
  if (bx < 672) {
    sdpa_path<52, 56, 28, 52, 1>(bx % 56, bx / 56, lk, Klg, ql, cosb, sinb,
                                 W_lkv, b_lkv, lk_out, sm);
  } else if (bx < 1920) {
    int id = bx - 672;
    sdpa_path<28, 104, 52, 1, 52>(id % 104, id / 104, rq, Krg, qr, cosb, sinb,
                                  W_rqv, b_rqv, rq_out, sm);
  } else {
    int id = bx - 1920;
    vb_path(id % 56, id / 56, v, vb2, sm);
  }
}

// ===========================================================================
// MID: fused L and R contractions (both 2x2 register-blocked)
// ===========================================================================
struct MidLShared { float qs[NB1][68]; float ks[FB1][68]; };
struct MidRShared { float ks[NB2][68]; float qs[FB2][68]; };
union MidShared { MidLShared L; MidRShared R; };

__device__ void L_path(int bid, const float* __restrict__ lq,
                       const float* __restrict__ cosb, const float* __restrict__ sinb,
                       const float* __restrict__ lk_out, float* __restrict__ Lbuf,
                       MidLShared& sh) {
  const int h = bid / (NF * NB2);
  const int rem = bid % (NF * NB2);
  const int a = rem / NB2, j = rem % NB2;
  const int tid = threadIdx.x;
  for (int idx = tid; idx < NB1 * 32; idx += 256) {
    int i = idx >> 5, mm = idx & 31;
    int srow = a * (NB1 * NB2) + i * NB2 + j;
    const float* xr = lq + (size_t)srow * STRIDE_HD + h * DD;
    float x0 = xr[2 * mm], x1 = xr[2 * mm + 1];
    float co = cosb[srow * 32 + mm], si = sinb[srow * 32 + mm];
    sh.qs[i][2 * mm]     = x0 * co - x1 * si;
    sh.qs[i][2 * mm + 1] = x1 * co + x0 * si;
  }
  for (int idx = tid; idx < FB1 * DD; idx += 256) {
    int r = idx >> 6, d = idx & 63;
    sh.ks[r][d] = lk_out[(size_t)r * STRIDE_HD + h * DD + d];
  }
  __syncthreads();
  for (int t = tid; t < NF * 14 * 14; t += 256) {
    int ff = t / 196, rr = t % 196;
    int it = rr / 14, kt = rr % 14;
    const float4* q0 = (const float4*)sh.qs[2 * it];
    const float4* q1 = (const float4*)sh.qs[2 * it + 1];
    const float4* k0 = (const float4*)sh.ks[ff * NB1 + 2 * kt];
    const float4* k1 = (const float4*)sh.ks[ff * NB1 + 2 * kt + 1];
    float a00 = 0.f, a01 = 0.f, a10 = 0.f, a11 = 0.f;
    #pragma unroll
    for (int d4 = 0; d4 < 16; ++d4) {
      float4 qa = q0[d4], qb = q1[d4], ka = k0[d4], kb = k1[d4];
      a00 += qa.x * ka.x + qa.y * ka.y + qa.z * ka.z + qa.w * ka.w;
      a01 += qa.x * kb.x + qa.y * kb.y + qa.z * kb.z + qa.w * kb.w;
      a10 += qb.x * ka.x + qb.y * ka.y + qb.z * ka.z + qb.w * ka.w;
      a11 += qb.x * kb.x + qb.y * kb.y + qb.z * kb.z + qb.w * kb.w;
    }
    size_t ob = (size_t)bid * (NF * NB1 * NB1) + (size_t)ff * (NB1 * NB1);
    Lbuf[ob + (size_t)(2 * it) * NB1 + 2 * kt]         = a00;
    Lbuf[ob + (size_t)(2 * it) * NB1 + 2 * kt + 1]     = a01;
    Lbuf[ob + (size_t)(2 * it + 1) * NB1 + 2 * kt]     = a10;
    Lbuf[ob + (size_t)(2 * it + 1) * NB1 + 2 * kt + 1] = a11;
  }
}

__device__ void R_path(int bid, const float* __restrict__ rk,
                       const float* __restrict__ cosb, const float* __restrict__ sinb,
                       const float* __restrict__ rq_out, float* __restrict__ Rbuf,
                       MidRShared& sh) {
  const int h = bid / FB1;
  const int fk = bid % FB1;
  const int f = fk / NB1, k = fk % NB1;
  const int tid = threadIdx.x;
  for (int idx = tid; idx < NB2 * 32; idx += 256) {
    int l = idx >> 5, mm = idx & 31;
    int srow = f * (NB1 * NB2) + k * NB2 + l;
    const float* xr = rk + (size_t)srow * STRIDE_HD + h * DD;
    float x0 = xr[2 * mm], x1 = xr[2 * mm + 1];
    float co = cosb[srow * 32 + mm], si = sinb[srow * 32 + mm];
    sh.ks[l][2 * mm]     = x0 * co - x1 * si;
    sh.ks[l][2 * mm + 1] = x1 * co + x0 * si;
  }
  for (int idx = tid; idx < FB2 * DD; idx += 256) {
    int r2 = idx >> 6, d = idx & 63;
    sh.qs[r2][d] = rq_out[(size_t)r2 * STRIDE_HD + h * DD + d];
  }
  __syncthreads();
  for (int t = tid; t < NF * 26 * 26; t += 256) {
    int aa = t / 676, rr = t % 676;
    int jt = rr / 26, lt = rr % 26;
    const float4* q0 = (const float4*)sh.qs[aa * NB2 + 2 * jt];
    const float4* q1 = (const float4*)sh.qs[aa * NB2 + 2 * jt + 1];
    const float4* k0 = (const float4*)sh.ks[2 * lt];
    const float4* k1 = (const float4*)sh.ks[2 * lt + 1];
    float a00 = 0.f, a01 = 0.f, a10 = 0.f, a11 = 0.f;
    #pragma unroll
    for (int d4 = 0; d4 < 16; ++d4) {
      float4 qa = q0[d4], qb = q1[d4], ka = k0[d4], kb = k1[d4];
      a00 += qa.x * ka.x + qa.y * ka.y + qa.z * ka.z + qa.w * ka.w;
      a01 += qa.x * kb.x + qa.y * kb.y + qa.z * kb.z + qa.w * kb.w;
      a10 += qb.x * ka.x + qb.y * ka.y + qb.z * ka.z + qb.w * ka.w;
      a11 += qb.x * kb.x + qb.y * kb.y + qb.z * kb.z + qb.w * kb.w;
    }
    size_t row0 = ((size_t)(h * NF + aa) * NB2 + 2 * jt) * (size_t)(NF * NB1 * NB2);
    size_t row1 = row0 + (size_t)(NF * NB1 * NB2);
    size_t cb = (size_t)fk * NB2 + 2 * lt;
    Rbuf[row0 + cb]     = a00;
    Rbuf[row0 + cb + 1] = a01;
    Rbuf[row1 + cb]     = a10;
    Rbuf[row1 + cb + 1] = a11;
  }
}

__global__ __launch_bounds__(256)
void k_mid(const float* __restrict__ lq, const float* __restrict__ rk,
           const float* __restrict__ cosb, const float* __restrict__ sinb,
           const float* __restrict__ lk_out, const float* __restrict__ rq_out,
           float* __restrict__ Lbuf, float* __restrict__ Rbuf) {
  __shared__ __align__(16) MidShared sh;
  const int bx = blockIdx.x;
  if (bx < 1248) L_path(bx, lq, cosb, sinb, lk_out, Lbuf, sh.L);
  else           R_path(bx - 1248, rk, cosb, sinb, rq_out, Rbuf, sh.R);
}

// ===========================================================================
// MAIN: factorized flash attention. 4 waves = 4 fk-segments; each wave
// computes P once and does 2 MFMAs (both d-halves). No in-loop barriers.
// ===========================================================================
struct MainPro { float Ls2T[2][28][36]; float Rs[56][64]; };
union MainShared { MainPro p; float epil[4][16][64]; };

__global__ __launch_bounds__(256, 4)
void k_main(const float* __restrict__ Lbuf, const float* __restrict__ Rbuf,
            const unsigned short* __restrict__ vb2, float* __restrict__ outp) {
  const int bid0 = blockIdx.x;
  const int bid = (bid0 & 7) * 156 + (bid0 >> 3);   // 1248 = 8*156, XCD-chunked
  const int h = bid / (NF * NB2);
  const int rem = bid % (NF * NB2);
  const int a = rem / NB2, j = rem % NB2;
  const int tid = threadIdx.x;
  const int lane = tid & 63;
  const int w = tid >> 6;

  __shared__ __align__(16) MainShared ms;
  __shared__ float m2s[32], Rmx[FB1], Rmn[FB1], els[4][32];

  const float SC = SCALEF * 1.44269504f;
  for (int idx = tid; idx < NF * NB1 * NB1; idx += 256) {
    int ff = idx / 784, r2 = idx % 784;
    int i = r2 / 28, kk = r2 % 28;
    ms.p.Ls2T[ff][kk][i] = Lbuf[(size_t)bid * (NF * NB1 * NB1) + idx] * SC;
  }
  if (tid < 224) {                                    // zero pad rows i=28..31
    int ff = tid / 112, r2 = tid % 112;
    ms.p.Ls2T[ff][r2 >> 2][28 + (r2 & 3)] = 0.f;
  }
  for (int idx = tid; idx < FB1 * 13; idx += 256) {
    int fk = idx / 13, lc = idx % 13;
    float4 vv = ((const float4*)(Rbuf + (size_t)bid * (NF * NB1 * NB2)))[idx];
    *(float4*)&ms.p.Rs[fk][lc * 4] = vv;
  }
  if (tid >= 252) m2s[tid - 224] = 0.f;               // pad rows 28..31
  __syncthreads();

  if (tid < 224) {                                    // col max/min of R
    int fk = tid >> 2, part = tid & 3;
    float mx = -1e30f, mn = 1e30f;
    for (int l = part * 13; l < part * 13 + 13; ++l) {
      float x = ms.p.Rs[fk][l];
      mx = fmaxf(mx, x); mn = fminf(mn, x);
    }
    mx = fmaxf(mx, __shfl_xor(mx, 1)); mn = fminf(mn, __shfl_xor(mn, 1));
    mx = fmaxf(mx, __shfl_xor(mx, 2)); mn = fminf(mn, __shfl_xor(mn, 2));
    if (part == 0) { Rmx[fk] = mx; Rmn[fk] = mn; }
  }
  __syncthreads();

  if (tid < 224) {                                    // exact row max (log2 units)
    int i = tid >> 3, s = tid & 7;
    float m = -1e30f;
    #pragma unroll
    for (int n = 0; n < 7; ++n) {
      int fk = s + 8 * n;
      int ff = (fk >= NB1) ? 1 : 0, kk = fk - ff * NB1;
      float Lv = ms.p.Ls2T[ff][kk][i];
      m = fmaxf(m, fmaxf(Lv * Rmx[fk], Lv * Rmn[fk]));
    }
    m = fmaxf(m, __shfl_xor(m, 1));
    m = fmaxf(m, __shfl_xor(m, 2));
    m = fmaxf(m, __shfl_xor(m, 4));
    if (s == 0) m2s[i] = m;
  }
  __syncthreads();

  const int row = lane & 31;
  const int hi = lane >> 5;
  const float nm = -m2s[row];
  // vb2 layout: [h][fk][l8][d][li], bf16x8 granule index = fk*512 + l8*64 + d
  const bf16x8* vw = (const bf16x8*)vb2 + (size_t)h * 28672 + hi * 64 + row;

  f32x16 acc0 = {0.f,0.f,0.f,0.f,0.f,0.f,0.f,0.f,0.f,0.f,0.f,0.f,0.f,0.f,0.f,0.f};
  f32x16 acc1 = {0.f,0.f,0.f,0.f,0.f,0.f,0.f,0.f,0.f,0.f,0.f,0.f,0.f,0.f,0.f,0.f};
  float lsum = 0.f;

  for (int t = 0; t < 14; ++t) {
    const int fk = w * 14 + t;
    const float Lv = ms.p.Ls2T[w >> 1][(w & 1) * 14 + t][row];
    const bf16x8* vp = vw + (size_t)fk * 512;
    #pragma unroll
    for (int ks = 0; ks < 4; ++ks) {
      const int k0 = ks * 16 + hi * 8;
      float4 ra = *(const float4*)&ms.p.Rs[fk][k0];
      float4 rb = *(const float4*)&ms.p.Rs[fk][k0 + 4];
      float p0 = EXP2(fmaf(Lv, ra.x, nm));
      float p1 = EXP2(fmaf(Lv, ra.y, nm));
      float p2 = EXP2(fmaf(Lv, ra.z, nm));
      float p3 = EXP2(fmaf(Lv, ra.w, nm));
      float p4 = EXP2(fmaf(Lv, rb.x, nm));
      float p5 = EXP2(fmaf(Lv, rb.y, nm));
      float p6 = EXP2(fmaf(Lv, rb.z, nm));
      float p7 = EXP2(fmaf(Lv, rb.w, nm));
      if (ks == 3) {                                  // l = 48+hi*8+idx; mask l>=52
        if (hi == 0) { p4 = 0.f; p5 = 0.f; p6 = 0.f; p7 = 0.f; }
        else { p0 = 0.f; p1 = 0.f; p2 = 0.f; p3 = 0.f;
               p4 = 0.f; p5 = 0.f; p6 = 0.f; p7 = 0.f; }
      }
      lsum += ((p0 + p1) + (p2 + p3)) + ((p4 + p5) + (p6 + p7));
      union { bf16x8 v8; __hip_bfloat162 h2[4]; } pk;
      pk.h2[0] = __float22bfloat162_rn(make_float2(p0, p1));
      pk.h2[1] = __float22bfloat162_rn(make_float2(p2, p3));
      pk.h2[2] = __float22bfloat162_rn(make_float2(p4, p5));
      pk.h2[3] = __float22bfloat162_rn(make_float2(p6, p7));
      bf16x8 b0 = vp[ks * 128];
      bf16x8 b1 = vp[ks * 128 + 32];
      acc0 = __builtin_amdgcn_mfma_f32_32x32x16_bf16(pk.v8, b0, acc0, 0, 0, 0);
      acc1 = __builtin_amdgcn_mfma_f32_32x32x16_bf16(pk.v8, b1, acc1, 0, 0, 0);
    }
  }

  lsum += __shfl_xor(lsum, 32);
  if (lane < 32) els[w][lane] = lsum;
  __syncthreads();                                     // Rs/Ls2T reads done; els visible

  // epilogue: 2 rounds (d-halves) of 4-segment reduction through LDS
  #pragma unroll
  for (int half = 0; half < 2; ++half) {
    if (half) __syncthreads();
    #pragma unroll
    for (int r = 0; r < 16; ++r)
      ms.epil[w][r][lane] = half ? acc1[r] : acc0[r];
    __syncthreads();
    #pragma unroll
    for (int q = 0; q < 4; ++q) {
      int r = (tid >> 6) + q * 4;
      int elane = tid & 63;
      float val = ms.epil[0][r][elane] + ms.epil[1][r][elane]
                + ms.epil[2][r][elane] + ms.epil[3][r][elane];
      int irow = (r & 3) + 8 * (r >> 2) + 4 * (elane >> 5);
      if (irow < NB1) {
        float li = 1.0f / (els[0][irow] + els[1][irow] + els[2][irow] + els[3][irow]);
        int srow = a * (NB1 * NB2) + irow * NB2 + j;
        int d = half * 32 + (elane & 31);
        outp[(size_t)srow * STRIDE_HD + h * DD + d] = val * li;
      }
    }
  }
}

// ---------------------------------------------------------------------------
extern "C" void kernel_launch(void* const* d_in, const int* in_sizes, int n_in,
                              void* d_out, int out_size, void* d_ws, size_t ws_size,
                              hipStream_t stream) {
  (void)in_sizes; (void)n_in; (void)out_size; (void)ws_size;
  const float* lq   = (const float*)d_in[0];
  const float* lk   = (const float*)d_in[1];
  const float* rq   = (const float*)d_in[2];
  const float* rk   = (const float*)d_in[3];
  const float* v    = (const float*)d_in[4];
  const float* cosb = (const float*)d_in[5];
  const float* sinb = (const float*)d_in[6];
  const float* W_lkq = (const float*)d_in[7];  const float* b_lkq = (const float*)d_in[8];
  const float* W_lkk = (const float*)d_in[9];  const float* b_lkk = (const float*)d_in[10];
  const float* W_lkv = (const float*)d_in[11]; const float* b_lkv = (const float*)d_in[12];
  const float* W_rqq = (const float*)d_in[13]; const float* b_rqq = (const float*)d_in[14];
  const float* W_rqk = (const float*)d_in[15]; const float* b_rqk = (const float*)d_in[16];
  const float* W_rqv = (const float*)d_in[17]; const float* b_rqv = (const float*)d_in[18];

  float* ws = (float*)d_ws;
  float* lk_out = ws;                                   // 43008
  float* rq_out = ws + 43008;                           // 79872
  float* Lbuf   = ws + 122880;                          // 1956864
  float* Rbuf   = ws + 2079744;                         // 3634176
  unsigned short* vb2 = (unsigned short*)(ws + 5713920);// 2752512 shorts
  float* ql     = ws + 7090176;                         // 43008
  float* qr     = ws + 7133184;                         // 79872
  // Klg/Krg alias the Lbuf/Rbuf space (dead before k_mid writes them)
  float* Klg = Lbuf;                                    // 2236416
  float* Krg = Lbuf + 2236416;                          // 2236416 (ends < Rbuf end)

  k_proj<<<1140, 256, 0, stream>>>(lk, rq, cosb, sinb,
      W_lkk, b_lkk, W_rqk, b_rqk, W_lkq, b_lkq, W_rqq, b_rqq,
      Klg, Krg, ql, qr);
  k_sv<<<2592, 256, 0, stream>>>(lk, rq, v, cosb, sinb, Klg, Krg, ql, qr,
      W_lkv, b_lkv, W_rqv, b_rqv, lk_out, rq_out, vb2);
  k_mid<<<1920, 256, 0, stream>>>(lq, rk, cosb, sinb, lk_out, rq_out, Lbuf, Rbuf);
  k_main<<<1248, 256, 0, stream>>>(Lbuf, Rbuf, vb2, (float*)d_out);
}